// Round 7
// baseline (4277.010 us; speedup 1.0000x reference)
//
#include <hip/hip_runtime.h>
#include <cstdint>
#include <cstddef>

#define NB 4
#define NN 8192
#define NPTS 2048
#define NSAMP 32
#define NC 128
#define CIN 131      // 3 + NC
#define NH1 64
#define NH2 128
#define NOUTC 128
#define GCELLS 4096  // 16x16x16 morton grid

typedef float v2f __attribute__((ext_vector_type(2)));

// Exact (numpy-order, contraction-free) squared distance:
// ((dx*dx + dy*dy) + dz*dz), round-to-nearest each op, no FMA.
__device__ __forceinline__ float d2_exact(float ax, float ay, float az,
                                          float bx, float by, float bz) {
  float dx = ax - bx, dy = ay - by, dz = az - bz;
  return __fadd_rn(__fadd_rn(__fmul_rn(dx, dx), __fmul_rn(dy, dy)),
                   __fmul_rn(dz, dz));
}

// ---- DPP cross-lane (VALU, no LDS). 0xB1=xor1 0x4E=xor2 0x141=half-mirror
// (xor7) 0x140=row-mirror (xor15). Masks {1,2,7,15} span a 16-lane butterfly
// (disjoint sets at every level); +shfl_xor 16/32 extends to 32/64.
#if __has_builtin(__builtin_amdgcn_mov_dpp)
template <int CTRL>
__device__ __forceinline__ float dppf(float v) {
  return __int_as_float(
      __builtin_amdgcn_mov_dpp(__float_as_int(v), CTRL, 0xF, 0xF, true));
}
template <int CTRL>
__device__ __forceinline__ int dppi(int v) {
  return __builtin_amdgcn_mov_dpp(v, CTRL, 0xF, 0xF, true);
}
#else
template <int CTRL>
__device__ __forceinline__ float dppf(float v) {
  const int m = (CTRL == 0xB1) ? 1 : (CTRL == 0x4E) ? 2 : (CTRL == 0x141) ? 7 : 15;
  return __shfl_xor(v, m);
}
template <int CTRL>
__device__ __forceinline__ int dppi(int v) {
  const int m = (CTRL == 0xB1) ? 1 : (CTRL == 0x4E) ? 2 : (CTRL == 0x141) ? 7 : 15;
  return __shfl_xor(v, m);
}
#endif

// total order: (value desc, index asc). distinct points => strict.
__device__ __forceinline__ bool tgt(float av, int ai, float bv, int bi) {
  return (av > bv) || (av == bv && ai < bi);
}

// argmax combine for (v,i) pairs (fallback kernel)
__device__ __forceinline__ void red_pair(float& bv, int& bi, float ov, int oi) {
  bool t = tgt(ov, oi, bv, bi);
  bv = t ? ov : bv;
  bi = t ? oi : bi;
}

// merge own sorted-2 list with incoming sorted-2 list (disjoint point sets).
__device__ __forceinline__ void mergeTop2_vals(float& v1, int& i1, float& v2,
                                               int& i2, float b1v, int b1i,
                                               float b2v, int b2i) {
  bool c = tgt(b1v, b1i, v1, i1);
  float w1v = c ? b1v : v1; int w1i = c ? b1i : i1;
  float ltv = c ? v1 : b1v; int lti = c ? i1 : b1i;   // loser of firsts
  float wsv = c ? b2v : v2; int wsi = c ? b2i : i2;   // winner's second
  bool d = tgt(ltv, lti, wsv, wsi);
  v1 = w1v; i1 = w1i;
  v2 = d ? ltv : wsv; i2 = d ? lti : wsi;
}
template <int CTRL>
__device__ __forceinline__ void mt2_dpp(float& v1, int& i1, float& v2, int& i2) {
  float b1v = dppf<CTRL>(v1); int b1i = dppi<CTRL>(i1);
  float b2v = dppf<CTRL>(v2); int b2i = dppi<CTRL>(i2);
  mergeTop2_vals(v1, i1, v2, i2, b1v, b1i, b2v, b2i);
}
__device__ __forceinline__ void mt2_shfl(float& v1, int& i1, float& v2, int& i2,
                                         int m) {
  float b1v = __shfl_xor(v1, m); int b1i = __shfl_xor(i1, m);
  float b2v = __shfl_xor(v2, m); int b2i = __shfl_xor(i2, m);
  mergeTop2_vals(v1, i1, v2, i2, b1v, b1i, b2v, b2i);
}

// full 10-field top-2 merge (entry merge, carries coords)
__device__ __forceinline__ void mergeTop2_full(
    float& v1, int& i1, float& x1, float& y1, float& z1,
    float& v2, int& i2, float& x2, float& y2, float& z2,
    float b1v, int b1i, float b1x, float b1y, float b1z,
    float b2v, int b2i, float b2x, float b2y, float b2z) {
  bool c = tgt(b1v, b1i, v1, i1);
  float w1v = c ? b1v : v1; int w1i = c ? b1i : i1;
  float w1x = c ? b1x : x1, w1y = c ? b1y : y1, w1z = c ? b1z : z1;
  float ltv = c ? v1 : b1v; int lti = c ? i1 : b1i;
  float ltx = c ? x1 : b1x, lty = c ? y1 : b1y, ltz = c ? z1 : b1z;
  float wsv = c ? b2v : v2; int wsi = c ? b2i : i2;
  float wsx = c ? b2x : x2, wsy = c ? b2y : y2, wsz = c ? b2z : z2;
  bool d = tgt(ltv, lti, wsv, wsi);
  v1 = w1v; i1 = w1i; x1 = w1x; y1 = w1y; z1 = w1z;
  v2 = d ? ltv : wsv; i2 = d ? lti : wsi;
  x2 = d ? ltx : wsx; y2 = d ? lty : wsy; z2 = d ? ltz : wsz;
}
template <int CTRL>
__device__ __forceinline__ void mt2f_dpp(float& v1, int& i1, float& x1,
                                         float& y1, float& z1, float& v2,
                                         int& i2, float& x2, float& y2,
                                         float& z2) {
  mergeTop2_full(v1, i1, x1, y1, z1, v2, i2, x2, y2, z2,
                 dppf<CTRL>(v1), dppi<CTRL>(i1), dppf<CTRL>(x1), dppf<CTRL>(y1),
                 dppf<CTRL>(z1), dppf<CTRL>(v2), dppi<CTRL>(i2), dppf<CTRL>(x2),
                 dppf<CTRL>(y2), dppf<CTRL>(z2));
}
__device__ __forceinline__ void mt2f_shfl(float& v1, int& i1, float& x1,
                                          float& y1, float& z1, float& v2,
                                          int& i2, float& x2, float& y2,
                                          float& z2, int m) {
  mergeTop2_full(v1, i1, x1, y1, z1, v2, i2, x2, y2, z2,
                 __shfl_xor(v1, m), __shfl_xor(i1, m), __shfl_xor(x1, m),
                 __shfl_xor(y1, m), __shfl_xor(z1, m), __shfl_xor(v2, m),
                 __shfl_xor(i2, m), __shfl_xor(x2, m), __shfl_xor(y2, m),
                 __shfl_xor(z2, m));
}

// 8->1 register select tree (compile-time indices only; rule-#20-safe)
#define SEL8(A, kk, out)                      \
  {                                           \
    float s0_ = ((kk) & 1) ? A[1] : A[0];     \
    float s1_ = ((kk) & 1) ? A[3] : A[2];     \
    float s2_ = ((kk) & 1) ? A[5] : A[4];     \
    float s3_ = ((kk) & 1) ? A[7] : A[6];     \
    float s4_ = ((kk) & 2) ? s1_ : s0_;       \
    float s5_ = ((kk) & 2) ? s3_ : s2_;       \
    out = ((kk) & 4) ? s5_ : s4_;             \
  }

// ---------------------------------------------------------------------------
// Spatial counting sort into 16^3 morton cells (one block per batch).
// Order within a cell is nondeterministic (LDS atomics) — harmless: FPS
// selection is order-independent (total order on (value, orig_idx)).
// ---------------------------------------------------------------------------
__device__ __forceinline__ int spread3(int v) {  // 4 bits -> every 3rd bit
  return (v & 1) | ((v & 2) << 2) | ((v & 4) << 4) | ((v & 8) << 6);
}

__global__ __launch_bounds__(1024, 1) void sort_kernel(
    const float* __restrict__ xyz, float* __restrict__ xs,
    float* __restrict__ ys, float* __restrict__ zs, int* __restrict__ io) {
  __shared__ int hist[GCELLS];
  __shared__ int cbase[GCELLS];
  __shared__ int wtot[16];
  __shared__ int woff[16];
  const int b = blockIdx.x;
  const int tid = threadIdx.x;
  const int lane = tid & 63;
  const int wid = tid >> 6;
  const float* xb = xyz + (size_t)b * NN * 3;
  for (int i = tid; i < GCELLS; i += 1024) hist[i] = 0;
  __syncthreads();
  int cell[8];
  float px[8], py[8], pz[8];
#pragma unroll
  for (int k = 0; k < 8; ++k) {
    int j = tid + (k << 10);
    float x = xb[j * 3 + 0], y = xb[j * 3 + 1], z = xb[j * 3 + 2];
    px[k] = x; py[k] = y; pz[k] = z;
    int cx = min(15, max(0, (int)(x * 16.0f)));
    int cy = min(15, max(0, (int)(y * 16.0f)));
    int cz = min(15, max(0, (int)(z * 16.0f)));
    cell[k] = spread3(cx) | (spread3(cy) << 1) | (spread3(cz) << 2);
    atomicAdd(&hist[cell[k]], 1);
  }
  __syncthreads();
  const int i0 = tid * 4;
  int h0 = hist[i0], h1 = hist[i0 + 1], h2 = hist[i0 + 2], h3 = hist[i0 + 3];
  int s4 = h0 + h1 + h2 + h3;
  int v = s4;
#pragma unroll
  for (int d = 1; d < 64; d <<= 1) {
    int o = __shfl_up(v, d);
    if (lane >= d) v += o;
  }
  if (lane == 63) wtot[wid] = v;
  __syncthreads();
  if (tid < 16) {
    int acc = 0;
    for (int w = 0; w < 16; ++w) {
      if (w == tid) woff[tid] = acc;
      acc += wtot[w];
    }
  }
  __syncthreads();
  int eb = woff[wid] + v - s4;
  cbase[i0] = eb;
  cbase[i0 + 1] = eb + h0;
  cbase[i0 + 2] = eb + h0 + h1;
  cbase[i0 + 3] = eb + h0 + h1 + h2;
  __syncthreads();
  for (int i = tid; i < GCELLS; i += 1024) hist[i] = 0;
  __syncthreads();
  const size_t bo = (size_t)b * NN;
#pragma unroll
  for (int k = 0; k < 8; ++k) {
    int pos = cbase[cell[k]] + atomicAdd(&hist[cell[k]], 1);
    xs[bo + pos] = px[k];
    ys[bo + pos] = py[k];
    zs[bo + pos] = pz[k];
    io[bo + pos] = tid + (k << 10);
  }
}

// ---------------------------------------------------------------------------
// FPS v5: exact speculative DOUBLE-POP, no pruning (R6 showed wave-level
// pruning never fires). 1024 threads/batch, 8 pts/thread register-resident.
// Per round: update D vs 1-2 popped centers (fminf chain in exact reference
// order), thread top-2 (v,i), wave top-2 butterfly, owner coord recovery,
// one barrier, 32-entry global top-2 merge with coords.
// Double-pop exactness: m1 = argmax (it IS center t). For p != m1,m2:
// (dist'_p, p) < (m2v, m2i) since dist only decreases. If d2(m2,m1) >= m2v
// then fminf leaves m2's value bitwise unchanged => m2 is bitwise the next
// argmax (first-index ties preserved by the (v desc, i asc) total order).
// ---------------------------------------------------------------------------
__global__ __launch_bounds__(1024, 1) void fps_kernel(
    const float* __restrict__ xyz, const float* __restrict__ xs,
    const float* __restrict__ ys, const float* __restrict__ zs,
    const int* __restrict__ io, float* __restrict__ newxyz) {
#pragma clang fp contract(off)
  const int b = blockIdx.x;
  const int tid = threadIdx.x;
  const int lane = tid & 63;
  const int wid = tid >> 6;
  const size_t bo = (size_t)b * NN;

  float X[8], Y[8], Z[8], D[8];
  int I[8];
#pragma unroll
  for (int k = 0; k < 8; ++k) {
    int s = tid * 8 + k;
    X[k] = xs[bo + s];
    Y[k] = ys[bo + s];
    Z[k] = zs[bo + s];
    I[k] = io[bo + s];
    D[k] = 1e30f;  // any init > 3 gives bitwise-identical first min
  }

  // [parity][entry 0..31][field v,i,x,y,z + pad to 9 (bank-conflict-free)]
  __shared__ float ebuf[2][32][9];

  const float* xb = xyz + (size_t)b * NN * 3;
  float p1x = xb[0], p1y = xb[1], p1z = xb[2];
  float p2x = 0.f, p2y = 0.f, p2z = 0.f;
  int npop = 1;
  if (tid == 0) {
    newxyz[(size_t)b * NPTS * 3 + 0] = p1x;
    newxyz[(size_t)b * NPTS * 3 + 1] = p1y;
    newxyz[(size_t)b * NPTS * 3 + 2] = p1z;
  }

  int t = 1, rnd = 0;
  while (t < NPTS) {
    const int par = rnd & 1;
    // ---- update + thread top-2 (v, orig idx) ----
    float n1v = -1.f, n2v = -1.f;
    int n1i = 0x7fffffff, n2i = 0x7fffffff;
    if (npop == 2) {
#pragma unroll
      for (int k = 0; k < 8; ++k) {
        float d1 = d2_exact(X[k], Y[k], Z[k], p1x, p1y, p1z);
        float d2 = d2_exact(X[k], Y[k], Z[k], p2x, p2y, p2z);
        float nd = fminf(fminf(D[k], d1), d2);  // exact 2-step reference order
        D[k] = nd;
        bool c1 = tgt(nd, I[k], n1v, n1i);
        bool c2 = tgt(nd, I[k], n2v, n2i);
        n2v = c1 ? n1v : (c2 ? nd : n2v);
        n2i = c1 ? n1i : (c2 ? I[k] : n2i);
        n1v = c1 ? nd : n1v;
        n1i = c1 ? I[k] : n1i;
      }
    } else {
#pragma unroll
      for (int k = 0; k < 8; ++k) {
        float d1 = d2_exact(X[k], Y[k], Z[k], p1x, p1y, p1z);
        float nd = fminf(D[k], d1);
        D[k] = nd;
        bool c1 = tgt(nd, I[k], n1v, n1i);
        bool c2 = tgt(nd, I[k], n2v, n2i);
        n2v = c1 ? n1v : (c2 ? nd : n2v);
        n2i = c1 ? n1i : (c2 ? I[k] : n2i);
        n1v = c1 ? nd : n1v;
        n1i = c1 ? I[k] : n1i;
      }
    }
    // ---- wave top-2 butterfly (disjoint sets at every level) ----
    float a1v = n1v, a2v = n2v;
    int a1i = n1i, a2i = n2i;
    mt2_dpp<0xB1>(a1v, a1i, a2v, a2i);
    mt2_dpp<0x4E>(a1v, a1i, a2v, a2i);
    mt2_dpp<0x141>(a1v, a1i, a2v, a2i);
    mt2_dpp<0x140>(a1v, a1i, a2v, a2i);
    mt2_shfl(a1v, a1i, a2v, a2i, 16);
    mt2_shfl(a1v, a1i, a2v, a2i, 32);
    // ---- owner coord recovery (unique owner thread per entry) ----
    int k1 = -1, k2 = -1;
#pragma unroll
    for (int k = 0; k < 8; ++k) {
      if (I[k] == a1i) k1 = k;
      if (I[k] == a2i) k2 = k;
    }
    if (k1 >= 0) {
      float ox, oy, oz;
      SEL8(X, k1, ox); SEL8(Y, k1, oy); SEL8(Z, k1, oz);
      ebuf[par][2 * wid][2] = ox;
      ebuf[par][2 * wid][3] = oy;
      ebuf[par][2 * wid][4] = oz;
    }
    if (k2 >= 0) {
      float ox, oy, oz;
      SEL8(X, k2, ox); SEL8(Y, k2, oy); SEL8(Z, k2, oz);
      ebuf[par][2 * wid + 1][2] = ox;
      ebuf[par][2 * wid + 1][3] = oy;
      ebuf[par][2 * wid + 1][4] = oz;
    }
    if (lane == 0) {
      ebuf[par][2 * wid][0] = a1v;
      ebuf[par][2 * wid][1] = __int_as_float(a1i);
      ebuf[par][2 * wid + 1][0] = a2v;
      ebuf[par][2 * wid + 1][1] = __int_as_float(a2i);
    }
    __syncthreads();
    // ---- global top-2 over 32 entries (each 32-half merges independently:
    //      levels xor{1,2,7,15,16} stay within the half -> no duplicates) ----
    const int e = lane & 31;
    float v1 = ebuf[par][e][0];
    int i1 = __float_as_int(ebuf[par][e][1]);
    float x1 = ebuf[par][e][2], y1 = ebuf[par][e][3], z1 = ebuf[par][e][4];
    float v2 = -1.f; int i2 = 0x7fffffff;
    float x2 = 0.f, y2 = 0.f, z2 = 0.f;
    mt2f_dpp<0xB1>(v1, i1, x1, y1, z1, v2, i2, x2, y2, z2);
    mt2f_dpp<0x4E>(v1, i1, x1, y1, z1, v2, i2, x2, y2, z2);
    mt2f_dpp<0x141>(v1, i1, x1, y1, z1, v2, i2, x2, y2, z2);
    mt2f_dpp<0x140>(v1, i1, x1, y1, z1, v2, i2, x2, y2, z2);
    mt2f_shfl(v1, i1, x1, y1, z1, v2, i2, x2, y2, z2, 16);
    // ---- pop 1 (always) + exact speculation for pop 2 ----
    bool pop2 = false;
    if (t + 1 < NPTS) pop2 = d2_exact(x2, y2, z2, x1, y1, z1) >= v2;
    if (tid == 0) {
      size_t o = ((size_t)b * NPTS + t) * 3;
      newxyz[o + 0] = x1; newxyz[o + 1] = y1; newxyz[o + 2] = z1;
      if (pop2) {
        newxyz[o + 3] = x2; newxyz[o + 4] = y2; newxyz[o + 5] = z2;
      }
    }
    p1x = x1; p1y = y1; p1z = z1;
    p2x = x2; p2y = y2; p2z = z2;
    npop = pop2 ? 2 : 1;
    t += npop;
    ++rnd;
    // one barrier/round; parity slots: round r's post-barrier reads of
    // ebuf[par] precede barrier(r+1), and ebuf[par] is rewritten only in
    // round r+2 (after barrier(r+1)) -> race-free.
  }
}

// ---------------------------------------------------------------------------
// Fallback FPS (no workspace): R2's 1024-thread register kernel.
// ---------------------------------------------------------------------------
__global__ __launch_bounds__(1024, 1) void fps_nosort_kernel(
    const float* __restrict__ xyz, float* __restrict__ newxyz) {
#pragma clang fp contract(off)
  const int b = blockIdx.x;
  const int tid = threadIdx.x;
  const int lane = tid & 63;
  const int wid = tid >> 6;
  const float* xb = xyz + (size_t)b * NN * 3;
  v2f x2[4], y2[4], z2[4], dd[4];
#pragma unroll
  for (int p = 0; p < 4; ++p) {
    int j0 = tid + ((2 * p) << 10);
    int j1 = tid + ((2 * p + 1) << 10);
    x2[p].x = xb[j0 * 3 + 0]; x2[p].y = xb[j1 * 3 + 0];
    y2[p].x = xb[j0 * 3 + 1]; y2[p].y = xb[j1 * 3 + 1];
    z2[p].x = xb[j0 * 3 + 2]; z2[p].y = xb[j1 * 3 + 2];
    dd[p].x = 1e10f; dd[p].y = 1e10f;
  }
  __shared__ float vbuf[2][16];
  __shared__ int ibuf[2][16];
  __shared__ float cbuf[2][16][3];
  float cx = xb[0], cy = xb[1], cz = xb[2];
  if (tid == 0) {
    newxyz[(size_t)b * NPTS * 3 + 0] = cx;
    newxyz[(size_t)b * NPTS * 3 + 1] = cy;
    newxyz[(size_t)b * NPTS * 3 + 2] = cz;
  }
  for (int t = 1; t < NPTS; ++t) {
    const int par = t & 1;
    float bv = -1.0f; int bi = 0;
    float bwx = 0.f, bwy = 0.f, bwz = 0.f;
#pragma unroll
    for (int p = 0; p < 4; ++p) {
      v2f dx = x2[p] - (v2f){cx, cx};
      v2f dy = y2[p] - (v2f){cy, cy};
      v2f dz = z2[p] - (v2f){cz, cz};
      v2f s = dx * dx + dy * dy + dz * dz;
      v2f nd;
      nd.x = fminf(dd[p].x, s.x);
      nd.y = fminf(dd[p].y, s.y);
      dd[p] = nd;
      { bool c = nd.x > bv;
        bv = c ? nd.x : bv; bi = c ? (tid + ((2 * p) << 10)) : bi;
        bwx = c ? x2[p].x : bwx; bwy = c ? y2[p].x : bwy; bwz = c ? z2[p].x : bwz; }
      { bool c = nd.y > bv;
        bv = c ? nd.y : bv; bi = c ? (tid + ((2 * p + 1) << 10)) : bi;
        bwx = c ? x2[p].y : bwx; bwy = c ? y2[p].y : bwy; bwz = c ? z2[p].y : bwz; }
    }
    red_pair(bv, bi, dppf<0xB1>(bv), dppi<0xB1>(bi));
    red_pair(bv, bi, dppf<0x4E>(bv), dppi<0x4E>(bi));
    red_pair(bv, bi, dppf<0x141>(bv), dppi<0x141>(bi));
    red_pair(bv, bi, dppf<0x140>(bv), dppi<0x140>(bi));
    red_pair(bv, bi, __shfl_xor(bv, 16), __shfl_xor(bi, 16));
    red_pair(bv, bi, __shfl_xor(bv, 32), __shfl_xor(bi, 32));
    if (tid == (bi & 1023)) {
      vbuf[par][wid] = bv; ibuf[par][wid] = bi;
      cbuf[par][wid][0] = bwx; cbuf[par][wid][1] = bwy; cbuf[par][wid][2] = bwz;
    }
    __syncthreads();
    float v2w = vbuf[par][lane & 15];
    int i2w = ibuf[par][lane & 15];
    red_pair(v2w, i2w, dppf<0xB1>(v2w), dppi<0xB1>(i2w));
    red_pair(v2w, i2w, dppf<0x4E>(v2w), dppi<0x4E>(i2w));
    red_pair(v2w, i2w, dppf<0x141>(v2w), dppi<0x141>(i2w));
    red_pair(v2w, i2w, dppf<0x140>(v2w), dppi<0x140>(i2w));
    const int slot = (i2w & 1023) >> 6;
    cx = cbuf[par][slot][0]; cy = cbuf[par][slot][1]; cz = cbuf[par][slot][2];
    if (tid == (i2w & 1023)) {
      size_t o = ((size_t)b * NPTS + t) * 3;
      newxyz[o + 0] = cx; newxyz[o + 1] = cy; newxyz[o + 2] = cz;
    }
  }
}

// ---------------------------------------------------------------------------
// Ball query: one wave per center; ballot scan in index order -> first 32 hits.
// ---------------------------------------------------------------------------
__global__ __launch_bounds__(256) void ballq_kernel(
    const float* __restrict__ xyz, const float* __restrict__ newxyz,
    int* __restrict__ bidx) {
  const int cid = blockIdx.x * 4 + (threadIdx.x >> 6);
  const int lane = threadIdx.x & 63;
  const int b = cid >> 11;
  const float* xb = xyz + (size_t)b * NN * 3;
  const float cx = newxyz[(size_t)cid * 3 + 0];
  const float cy = newxyz[(size_t)cid * 3 + 1];
  const float cz = newxyz[(size_t)cid * 3 + 2];
  int* ob = bidx + (size_t)cid * NSAMP;
  int total = 0;
  int first = -1;
  for (int c0 = 0; c0 < NN; c0 += 64) {
    int j = c0 + lane;
    float xx = xb[j * 3 + 0], yy = xb[j * 3 + 1], zz = xb[j * 3 + 2];
    float d2 = d2_exact(cx, cy, cz, xx, yy, zz);
    bool in = d2 <= 0.04f;
    unsigned long long m = __ballot(in);
    if (first < 0 && m) first = c0 + __builtin_ctzll(m);
    int pos = total + __popcll(m & ((1ull << lane) - 1ull));
    if (in && pos < NSAMP) ob[pos] = j;
    total += __popcll(m);
    if (total >= NSAMP) break;
  }
  if (total < NSAMP && lane < NSAMP - total) ob[total + lane] = first;
}

// ---------------------------------------------------------------------------
__global__ void tw_kernel(const float* __restrict__ W1, const float* __restrict__ W2,
                          const float* __restrict__ Wsa, float* __restrict__ w1t,
                          float* __restrict__ w2t, float* __restrict__ wsat) {
  int i = blockIdx.x * blockDim.x + threadIdx.x;
  if (i < CIN * NH1) w1t[i] = W1[(i % NH1) * CIN + (i / NH1)];
  if (i < NH1 * NH2) w2t[i] = W2[(i % NH2) * NH1 + (i / NH2)];
  if (i < NH2 * NOUTC) wsat[i] = Wsa[(i % NOUTC) * NH2 + (i / NOUTC)];
}

__global__ void tfeat_kernel(const float* __restrict__ feat, float* __restrict__ featT) {
  __shared__ float tile[32][33];
  const int b = blockIdx.z;
  const int n0 = blockIdx.x * 32, c0 = blockIdx.y * 32;
  const int tx = threadIdx.x, ty = threadIdx.y;
#pragma unroll
  for (int r = 0; r < 4; ++r)
    tile[ty + r * 8][tx] = feat[((size_t)b * NC + c0 + ty + r * 8) * NN + n0 + tx];
  __syncthreads();
#pragma unroll
  for (int r = 0; r < 4; ++r)
    featT[((size_t)b * NN + n0 + ty + r * 8) * NC + c0 + tx] = tile[tx][ty + r * 8];
}

// ---------------------------------------------------------------------------
// Fused gather + MLP(64,128) + maxpool + final linear, one block per center.
// ---------------------------------------------------------------------------
#define HS 36
__global__ __launch_bounds__(256) void mlp_kernel(
    const float* __restrict__ xyz, const float* __restrict__ fsrc,
    const float* __restrict__ newxyz, const int* __restrict__ bidx,
    const float* __restrict__ w1t, const float* __restrict__ b1,
    const float* __restrict__ w2t, const float* __restrict__ b2,
    const float* __restrict__ wsat, const float* __restrict__ bsa,
    float* __restrict__ out1, int useT) {
  __shared__ float h[CIN * HS];
  __shared__ float h1[NH1 * HS];
  __shared__ float pl[256];
  __shared__ float pooled[NH2];
  __shared__ int sidx[NSAMP];
  __shared__ float sc[3];
  const int cid = blockIdx.x;
  const int b = cid >> 11;
  const int s = cid & 2047;
  const int tid = threadIdx.x;
  if (tid < NSAMP) sidx[tid] = bidx[(size_t)cid * NSAMP + tid];
  if (tid < 3) sc[tid] = newxyz[(size_t)cid * 3 + tid];
  __syncthreads();
  {
    const int ss = tid >> 3, q = tid & 7;
    const int j = sidx[ss];
    if (useT) {
      const float4* fr = (const float4*)(fsrc + ((size_t)b * NN + j) * NC + q * 16);
#pragma unroll
      for (int u = 0; u < 4; ++u) {
        float4 v = fr[u];
        int c = 3 + q * 16 + u * 4;
        h[(c + 0) * HS + ss] = v.x;
        h[(c + 1) * HS + ss] = v.y;
        h[(c + 2) * HS + ss] = v.z;
        h[(c + 3) * HS + ss] = v.w;
      }
    } else {
      for (int u = 0; u < 16; ++u) {
        int c = q * 16 + u;
        h[(3 + c) * HS + ss] = fsrc[((size_t)b * NC + c) * NN + j];
      }
    }
    if (q == 0) {
      const float* pr = xyz + ((size_t)b * NN + j) * 3;
      h[0 * HS + ss] = pr[0] - sc[0];
      h[1 * HS + ss] = pr[1] - sc[1];
      h[2 * HS + ss] = pr[2] - sc[2];
    }
  }
  __syncthreads();
  {
    const int o = tid & 63, sg = tid >> 6;
    float acc[8];
    const float bb = b1[o];
#pragma unroll
    for (int i = 0; i < 8; ++i) acc[i] = bb;
    const float4* hb = (const float4*)&h[sg * 8];
    for (int k = 0; k < CIN; ++k) {
      float w = w1t[k * NH1 + o];
      float4 a = hb[k * (HS / 4) + 0];
      float4 c = hb[k * (HS / 4) + 1];
      acc[0] = fmaf(w, a.x, acc[0]); acc[1] = fmaf(w, a.y, acc[1]);
      acc[2] = fmaf(w, a.z, acc[2]); acc[3] = fmaf(w, a.w, acc[3]);
      acc[4] = fmaf(w, c.x, acc[4]); acc[5] = fmaf(w, c.y, acc[5]);
      acc[6] = fmaf(w, c.z, acc[6]); acc[7] = fmaf(w, c.w, acc[7]);
    }
#pragma unroll
    for (int i = 0; i < 8; ++i) h1[o * HS + sg * 8 + i] = fmaxf(acc[i], 0.0f);
  }
  __syncthreads();
  {
    const int o = tid & 127, sg = tid >> 7;
    float acc[16];
    const float bb = b2[o];
#pragma unroll
    for (int i = 0; i < 16; ++i) acc[i] = bb;
    const float4* hb = (const float4*)&h1[sg * 16];
    for (int k = 0; k < NH1; ++k) {
      float w = w2t[k * NH2 + o];
#pragma unroll
      for (int u = 0; u < 4; ++u) {
        float4 a = hb[k * (HS / 4) + u];
        acc[u * 4 + 0] = fmaf(w, a.x, acc[u * 4 + 0]);
        acc[u * 4 + 1] = fmaf(w, a.y, acc[u * 4 + 1]);
        acc[u * 4 + 2] = fmaf(w, a.z, acc[u * 4 + 2]);
        acc[u * 4 + 3] = fmaf(w, a.w, acc[u * 4 + 3]);
      }
    }
    float pm = acc[0];
#pragma unroll
    for (int i = 1; i < 16; ++i) pm = fmaxf(pm, acc[i]);
    pl[sg * 128 + o] = pm;
  }
  __syncthreads();
  if (tid < NH2) pooled[tid] = fmaxf(fmaxf(pl[tid], pl[128 + tid]), 0.0f);
  __syncthreads();
  if (tid < NOUTC) {
    float acc = bsa[tid];
    for (int k = 0; k < NH2; ++k) acc = fmaf(pooled[k], wsat[k * NOUTC + tid], acc);
    out1[((size_t)b * NOUTC + tid) * NPTS + s] = acc;
  }
}

extern "C" void kernel_launch(void* const* d_in, const int* in_sizes, int n_in,
                              void* d_out, int out_size, void* d_ws, size_t ws_size,
                              hipStream_t stream) {
  const float* xyz = (const float*)d_in[0];
  const float* feat = (const float*)d_in[1];
  const float* W1 = (const float*)d_in[2];
  const float* b1 = (const float*)d_in[3];
  const float* W2 = (const float*)d_in[4];
  const float* b2 = (const float*)d_in[5];
  const float* Wsa = (const float*)d_in[6];
  const float* bsa = (const float*)d_in[7];
  float* out = (float*)d_out;
  float* newxyz = out;                       // (B, NPTS, 3)
  float* out1 = out + (size_t)NB * NPTS * 3; // (B, OUT, NPTS)

  const size_t sort_f = (size_t)NB * NN * 4;  // xs, ys, zs, io
  const size_t small_f = (size_t)CIN * NH1 + NH1 * NH2 + NH2 * NOUTC +
                         (size_t)NB * NPTS * NSAMP;
  const size_t featT_f = (size_t)NB * NN * NC;

  float* ws = (float*)d_ws;
  bool useSort = ws_size >= (sort_f + small_f) * 4;
  bool useT = ws_size >= (sort_f + small_f + featT_f) * 4;

  float* xs = ws;
  float* ysr = xs + (size_t)NB * NN;
  float* zsr = ysr + (size_t)NB * NN;
  int* iosr = (int*)(zsr + (size_t)NB * NN);
  float* base2 = useSort ? (ws + sort_f) : ws;
  float* w1t = base2;
  float* w2t = w1t + CIN * NH1;
  float* wsat = w2t + NH1 * NH2;
  int* bidx = (int*)(wsat + NH2 * NOUTC);
  float* featT = (float*)(bidx + (size_t)NB * NPTS * NSAMP);

  tw_kernel<<<64, 256, 0, stream>>>(W1, W2, Wsa, w1t, w2t, wsat);
  if (useT)
    tfeat_kernel<<<dim3(NN / 32, NC / 32, NB), dim3(32, 8), 0, stream>>>(feat, featT);
  if (useSort) {
    sort_kernel<<<NB, 1024, 0, stream>>>(xyz, xs, ysr, zsr, iosr);
    fps_kernel<<<NB, 1024, 0, stream>>>(xyz, xs, ysr, zsr, iosr, newxyz);
  } else {
    fps_nosort_kernel<<<NB, 1024, 0, stream>>>(xyz, newxyz);
  }
  ballq_kernel<<<NB * NPTS / 4, 256, 0, stream>>>(xyz, newxyz, bidx);
  mlp_kernel<<<NB * NPTS, 256, 0, stream>>>(xyz, useT ? featT : feat, newxyz, bidx,
                                            w1t, b1, w2t, b2, wsat, bsa, out1,
                                            (int)useT);
}

// Round 8
// 3838.358 us; speedup vs baseline: 1.1143x; 1.1143x over previous
//
#include <hip/hip_runtime.h>
#include <cstdint>
#include <cstddef>

#define NB 4
#define NN 8192
#define NPTS 2048
#define NSAMP 32
#define NC 128
#define CIN 131      // 3 + NC
#define NH1 64
#define NH2 128
#define NOUTC 128
#define GCELLS 4096  // 16x16x16 morton grid

typedef float v2f __attribute__((ext_vector_type(2)));

// Exact (numpy-order, contraction-free) squared distance:
// ((dx*dx + dy*dy) + dz*dz), round-to-nearest each op, no FMA.
__device__ __forceinline__ float d2_exact(float ax, float ay, float az,
                                          float bx, float by, float bz) {
  float dx = ax - bx, dy = ay - by, dz = az - bz;
  return __fadd_rn(__fadd_rn(__fmul_rn(dx, dx), __fmul_rn(dy, dy)),
                   __fmul_rn(dz, dz));
}

// ---- DPP cross-lane (VALU, no LDS). 0xB1=xor1 0x4E=xor2 0x141=half-mirror
// (xor7) 0x140=row-mirror (xor15). {1,2,7,15} spans a 16-lane butterfly;
// +shfl_xor 16/32 extends to the full wave. (Validated exact in R2-R7.)
#if __has_builtin(__builtin_amdgcn_mov_dpp)
template <int CTRL>
__device__ __forceinline__ float dppf(float v) {
  return __int_as_float(
      __builtin_amdgcn_mov_dpp(__float_as_int(v), CTRL, 0xF, 0xF, true));
}
template <int CTRL>
__device__ __forceinline__ int dppi(int v) {
  return __builtin_amdgcn_mov_dpp(v, CTRL, 0xF, 0xF, true);
}
#else
template <int CTRL>
__device__ __forceinline__ float dppf(float v) {
  const int m = (CTRL == 0xB1) ? 1 : (CTRL == 0x4E) ? 2 : (CTRL == 0x141) ? 7 : 15;
  return __shfl_xor(v, m);
}
template <int CTRL>
__device__ __forceinline__ int dppi(int v) {
  const int m = (CTRL == 0xB1) ? 1 : (CTRL == 0x4E) ? 2 : (CTRL == 0x141) ? 7 : 15;
  return __shfl_xor(v, m);
}
#endif

// total order: (value desc, index asc). distinct points => strict.
__device__ __forceinline__ bool tgt(float av, int ai, float bv, int bi) {
  return (av > bv) || (av == bv && ai < bi);
}

// argmax combine for (v,i) pairs
__device__ __forceinline__ void red_pair(float& bv, int& bi, float ov, int oi) {
  bool t = tgt(ov, oi, bv, bi);
  bv = t ? ov : bv;
  bi = t ? oi : bi;
}
// same comparator, carrying coords through row-local DPP (16-slot merge)
template <int CTRL>
__device__ __forceinline__ void red5(float& v, int& i, float& x, float& y,
                                     float& z) {
  float ov = dppf<CTRL>(v);
  int oi = dppi<CTRL>(i);
  float ox = dppf<CTRL>(x), oy = dppf<CTRL>(y), oz = dppf<CTRL>(z);
  bool t = tgt(ov, oi, v, i);
  v = t ? ov : v; i = t ? oi : i;
  x = t ? ox : x; y = t ? oy : y; z = t ? oz : z;
}

// 8->1 register select tree (compile-time indices only; scratch-safe)
#define SEL8(A, kk, out)                      \
  {                                           \
    float s0_ = ((kk) & 1) ? A[1] : A[0];     \
    float s1_ = ((kk) & 1) ? A[3] : A[2];     \
    float s2_ = ((kk) & 1) ? A[5] : A[4];     \
    float s3_ = ((kk) & 1) ? A[7] : A[6];     \
    float s4_ = ((kk) & 2) ? s1_ : s0_;       \
    float s5_ = ((kk) & 2) ? s3_ : s2_;       \
    out = ((kk) & 4) ? s5_ : s4_;             \
  }

// ---------------------------------------------------------------------------
// Spatial counting sort into 16^3 morton cells (one block per batch).
// Order within a cell is nondeterministic (LDS atomics) — harmless: FPS
// selection is order-independent (total order on (value, orig_idx)).
// ---------------------------------------------------------------------------
__device__ __forceinline__ int spread3(int v) {  // 4 bits -> every 3rd bit
  return (v & 1) | ((v & 2) << 2) | ((v & 4) << 4) | ((v & 8) << 6);
}

__global__ __launch_bounds__(1024, 1) void sort_kernel(
    const float* __restrict__ xyz, float* __restrict__ xs,
    float* __restrict__ ys, float* __restrict__ zs, int* __restrict__ io) {
  __shared__ int hist[GCELLS];
  __shared__ int cbase[GCELLS];
  __shared__ int wtot[16];
  __shared__ int woff[16];
  const int b = blockIdx.x;
  const int tid = threadIdx.x;
  const int lane = tid & 63;
  const int wid = tid >> 6;
  const float* xb = xyz + (size_t)b * NN * 3;
  for (int i = tid; i < GCELLS; i += 1024) hist[i] = 0;
  __syncthreads();
  int cell[8];
  float px[8], py[8], pz[8];
#pragma unroll
  for (int k = 0; k < 8; ++k) {
    int j = tid + (k << 10);
    float x = xb[j * 3 + 0], y = xb[j * 3 + 1], z = xb[j * 3 + 2];
    px[k] = x; py[k] = y; pz[k] = z;
    int cx = min(15, max(0, (int)(x * 16.0f)));
    int cy = min(15, max(0, (int)(y * 16.0f)));
    int cz = min(15, max(0, (int)(z * 16.0f)));
    cell[k] = spread3(cx) | (spread3(cy) << 1) | (spread3(cz) << 2);
    atomicAdd(&hist[cell[k]], 1);
  }
  __syncthreads();
  const int i0 = tid * 4;
  int h0 = hist[i0], h1 = hist[i0 + 1], h2 = hist[i0 + 2], h3 = hist[i0 + 3];
  int s4 = h0 + h1 + h2 + h3;
  int v = s4;
#pragma unroll
  for (int d = 1; d < 64; d <<= 1) {
    int o = __shfl_up(v, d);
    if (lane >= d) v += o;
  }
  if (lane == 63) wtot[wid] = v;
  __syncthreads();
  if (tid < 16) {
    int acc = 0;
    for (int w = 0; w < 16; ++w) {
      if (w == tid) woff[tid] = acc;
      acc += wtot[w];
    }
  }
  __syncthreads();
  int eb = woff[wid] + v - s4;
  cbase[i0] = eb;
  cbase[i0 + 1] = eb + h0;
  cbase[i0 + 2] = eb + h0 + h1;
  cbase[i0 + 3] = eb + h0 + h1 + h2;
  __syncthreads();
  for (int i = tid; i < GCELLS; i += 1024) hist[i] = 0;
  __syncthreads();
  const size_t bo = (size_t)b * NN;
#pragma unroll
  for (int k = 0; k < 8; ++k) {
    int pos = cbase[cell[k]] + atomicAdd(&hist[cell[k]], 1);
    xs[bo + pos] = px[k];
    ys[bo + pos] = py[k];
    zs[bo + pos] = pz[k];
    io[bo + pos] = tid + (k << 10);
  }
}

// ---------------------------------------------------------------------------
// FPS v6: single-pop, no pruning, TWO barriers/step with wave0-only merge.
//  - body: 8 pts/thread, track (v, orig idx, reg slot) only (no coord carry).
//  - wave allreduce (v,i); unique owner lane (bi==ri) publishes coords via
//    compile-time SEL8 + its wave slot — no ballot, no shfl.
//  - bar1 -> wave 0 alone merges 16 slots (others idle at bar2, freeing all
//    issue slots), writes newxyz[t] + 3-float broadcast slot -> bar2.
//  - no parity buffers: slot writes (after bar2(t)) cannot race wave0's
//    reads (before bar2(t)); fin reads (after bar2(t)) precede bar1(t+1)
//    after which fin(t+1) is written.
// Arithmetic identical to validated rounds: d2_exact, fminf, (v desc, i asc).
// ---------------------------------------------------------------------------
__global__ __launch_bounds__(1024, 1) void fps_kernel(
    const float* __restrict__ xyz, const float* __restrict__ xs,
    const float* __restrict__ ys, const float* __restrict__ zs,
    const int* __restrict__ io, float* __restrict__ newxyz) {
#pragma clang fp contract(off)
  const int b = blockIdx.x;
  const int tid = threadIdx.x;
  const int lane = tid & 63;
  const int wid = tid >> 6;
  const size_t bo = (size_t)b * NN;

  float X[8], Y[8], Z[8], D[8];
  int I[8];
#pragma unroll
  for (int k = 0; k < 8; ++k) {
    int s = tid * 8 + k;
    X[k] = xs[bo + s];
    Y[k] = ys[bo + s];
    Z[k] = zs[bo + s];
    I[k] = io[bo + s];
    D[k] = 1e30f;  // any init > 3 gives bitwise-identical first min
  }

  __shared__ float sv[16];
  __shared__ int si[16];
  __shared__ float sx[16], sy[16], sz[16];
  __shared__ float fin[3];

  const float* xb = xyz + (size_t)b * NN * 3;
  float cx = xb[0], cy = xb[1], cz = xb[2];
  if (tid == 0) {
    newxyz[(size_t)b * NPTS * 3 + 0] = cx;
    newxyz[(size_t)b * NPTS * 3 + 1] = cy;
    newxyz[(size_t)b * NPTS * 3 + 2] = cz;
  }

  for (int t = 1; t < NPTS; ++t) {
    // ---- body: update D, track thread best (v, i, reg slot) ----
    float bv = -1.0f;
    int bi = 0x7fffffff;
    int kw = 0;
#pragma unroll
    for (int k = 0; k < 8; ++k) {
      float dd = d2_exact(X[k], Y[k], Z[k], cx, cy, cz);
      float nd = fminf(D[k], dd);
      D[k] = nd;
      bool c = tgt(nd, I[k], bv, bi);
      bv = c ? nd : bv;
      bi = c ? I[k] : bi;
      kw = c ? k : kw;
    }
    // ---- wave allreduce on (v, orig idx) ----
    float rv = bv;
    int ri = bi;
    red_pair(rv, ri, dppf<0xB1>(rv), dppi<0xB1>(ri));
    red_pair(rv, ri, dppf<0x4E>(rv), dppi<0x4E>(ri));
    red_pair(rv, ri, dppf<0x141>(rv), dppi<0x141>(ri));
    red_pair(rv, ri, dppf<0x140>(rv), dppi<0x140>(ri));
    red_pair(rv, ri, __shfl_xor(rv, 16), __shfl_xor(ri, 16));
    red_pair(rv, ri, __shfl_xor(rv, 32), __shfl_xor(ri, 32));
    // ---- unique owner lane publishes its wave's entry directly ----
    if (bi == ri) {  // orig indices are partitioned -> exactly one lane
      float ox, oy, oz;
      SEL8(X, kw, ox);
      SEL8(Y, kw, oy);
      SEL8(Z, kw, oz);
      sv[wid] = rv;
      si[wid] = ri;
      sx[wid] = ox;
      sy[wid] = oy;
      sz[wid] = oz;
    }
    __syncthreads();  // bar1: entries visible to wave 0
    if (wid == 0) {   // wave 0 alone merges; parked waves free the SIMDs
      const int e = lane & 15;
      float v = sv[e];
      int i = si[e];
      float xx = sx[e], yy = sy[e], zz = sz[e];
      red5<0xB1>(v, i, xx, yy, zz);
      red5<0x4E>(v, i, xx, yy, zz);
      red5<0x141>(v, i, xx, yy, zz);
      red5<0x140>(v, i, xx, yy, zz);
      if (lane == 0) {
        fin[0] = xx;
        fin[1] = yy;
        fin[2] = zz;
        size_t o = ((size_t)b * NPTS + t) * 3;
        newxyz[o + 0] = xx;
        newxyz[o + 1] = yy;
        newxyz[o + 2] = zz;
      }
    }
    __syncthreads();  // bar2: winner broadcast ready
    cx = fin[0];
    cy = fin[1];
    cz = fin[2];
  }
}

// ---------------------------------------------------------------------------
// Fallback FPS (no workspace): R2's 1024-thread register kernel.
// ---------------------------------------------------------------------------
__global__ __launch_bounds__(1024, 1) void fps_nosort_kernel(
    const float* __restrict__ xyz, float* __restrict__ newxyz) {
#pragma clang fp contract(off)
  const int b = blockIdx.x;
  const int tid = threadIdx.x;
  const int lane = tid & 63;
  const int wid = tid >> 6;
  const float* xb = xyz + (size_t)b * NN * 3;
  v2f x2[4], y2[4], z2[4], dd[4];
#pragma unroll
  for (int p = 0; p < 4; ++p) {
    int j0 = tid + ((2 * p) << 10);
    int j1 = tid + ((2 * p + 1) << 10);
    x2[p].x = xb[j0 * 3 + 0]; x2[p].y = xb[j1 * 3 + 0];
    y2[p].x = xb[j0 * 3 + 1]; y2[p].y = xb[j1 * 3 + 1];
    z2[p].x = xb[j0 * 3 + 2]; z2[p].y = xb[j1 * 3 + 2];
    dd[p].x = 1e10f; dd[p].y = 1e10f;
  }
  __shared__ float vbuf[2][16];
  __shared__ int ibuf[2][16];
  __shared__ float cbuf[2][16][3];
  float cx = xb[0], cy = xb[1], cz = xb[2];
  if (tid == 0) {
    newxyz[(size_t)b * NPTS * 3 + 0] = cx;
    newxyz[(size_t)b * NPTS * 3 + 1] = cy;
    newxyz[(size_t)b * NPTS * 3 + 2] = cz;
  }
  for (int t = 1; t < NPTS; ++t) {
    const int par = t & 1;
    float bv = -1.0f; int bi = 0;
    float bwx = 0.f, bwy = 0.f, bwz = 0.f;
#pragma unroll
    for (int p = 0; p < 4; ++p) {
      v2f dx = x2[p] - (v2f){cx, cx};
      v2f dy = y2[p] - (v2f){cy, cy};
      v2f dz = z2[p] - (v2f){cz, cz};
      v2f s = dx * dx + dy * dy + dz * dz;
      v2f nd;
      nd.x = fminf(dd[p].x, s.x);
      nd.y = fminf(dd[p].y, s.y);
      dd[p] = nd;
      { bool c = nd.x > bv;
        bv = c ? nd.x : bv; bi = c ? (tid + ((2 * p) << 10)) : bi;
        bwx = c ? x2[p].x : bwx; bwy = c ? y2[p].x : bwy; bwz = c ? z2[p].x : bwz; }
      { bool c = nd.y > bv;
        bv = c ? nd.y : bv; bi = c ? (tid + ((2 * p + 1) << 10)) : bi;
        bwx = c ? x2[p].y : bwx; bwy = c ? y2[p].y : bwy; bwz = c ? z2[p].y : bwz; }
    }
    red_pair(bv, bi, dppf<0xB1>(bv), dppi<0xB1>(bi));
    red_pair(bv, bi, dppf<0x4E>(bv), dppi<0x4E>(bi));
    red_pair(bv, bi, dppf<0x141>(bv), dppi<0x141>(bi));
    red_pair(bv, bi, dppf<0x140>(bv), dppi<0x140>(bi));
    red_pair(bv, bi, __shfl_xor(bv, 16), __shfl_xor(bi, 16));
    red_pair(bv, bi, __shfl_xor(bv, 32), __shfl_xor(bi, 32));
    if (tid == (bi & 1023)) {
      vbuf[par][wid] = bv; ibuf[par][wid] = bi;
      cbuf[par][wid][0] = bwx; cbuf[par][wid][1] = bwy; cbuf[par][wid][2] = bwz;
    }
    __syncthreads();
    float v2w = vbuf[par][lane & 15];
    int i2w = ibuf[par][lane & 15];
    red_pair(v2w, i2w, dppf<0xB1>(v2w), dppi<0xB1>(i2w));
    red_pair(v2w, i2w, dppf<0x4E>(v2w), dppi<0x4E>(i2w));
    red_pair(v2w, i2w, dppf<0x141>(v2w), dppi<0x141>(i2w));
    red_pair(v2w, i2w, dppf<0x140>(v2w), dppi<0x140>(i2w));
    const int slot = (i2w & 1023) >> 6;
    cx = cbuf[par][slot][0]; cy = cbuf[par][slot][1]; cz = cbuf[par][slot][2];
    if (tid == (i2w & 1023)) {
      size_t o = ((size_t)b * NPTS + t) * 3;
      newxyz[o + 0] = cx; newxyz[o + 1] = cy; newxyz[o + 2] = cz;
    }
  }
}

// ---------------------------------------------------------------------------
// Ball query: one wave per center; ballot scan in index order -> first 32 hits.
// ---------------------------------------------------------------------------
__global__ __launch_bounds__(256) void ballq_kernel(
    const float* __restrict__ xyz, const float* __restrict__ newxyz,
    int* __restrict__ bidx) {
  const int cid = blockIdx.x * 4 + (threadIdx.x >> 6);
  const int lane = threadIdx.x & 63;
  const int b = cid >> 11;
  const float* xb = xyz + (size_t)b * NN * 3;
  const float cx = newxyz[(size_t)cid * 3 + 0];
  const float cy = newxyz[(size_t)cid * 3 + 1];
  const float cz = newxyz[(size_t)cid * 3 + 2];
  int* ob = bidx + (size_t)cid * NSAMP;
  int total = 0;
  int first = -1;
  for (int c0 = 0; c0 < NN; c0 += 64) {
    int j = c0 + lane;
    float xx = xb[j * 3 + 0], yy = xb[j * 3 + 1], zz = xb[j * 3 + 2];
    float d2 = d2_exact(cx, cy, cz, xx, yy, zz);
    bool in = d2 <= 0.04f;
    unsigned long long m = __ballot(in);
    if (first < 0 && m) first = c0 + __builtin_ctzll(m);
    int pos = total + __popcll(m & ((1ull << lane) - 1ull));
    if (in && pos < NSAMP) ob[pos] = j;
    total += __popcll(m);
    if (total >= NSAMP) break;
  }
  if (total < NSAMP && lane < NSAMP - total) ob[total + lane] = first;
}

// ---------------------------------------------------------------------------
__global__ void tw_kernel(const float* __restrict__ W1, const float* __restrict__ W2,
                          const float* __restrict__ Wsa, float* __restrict__ w1t,
                          float* __restrict__ w2t, float* __restrict__ wsat) {
  int i = blockIdx.x * blockDim.x + threadIdx.x;
  if (i < CIN * NH1) w1t[i] = W1[(i % NH1) * CIN + (i / NH1)];
  if (i < NH1 * NH2) w2t[i] = W2[(i % NH2) * NH1 + (i / NH2)];
  if (i < NH2 * NOUTC) wsat[i] = Wsa[(i % NOUTC) * NH2 + (i / NOUTC)];
}

__global__ void tfeat_kernel(const float* __restrict__ feat, float* __restrict__ featT) {
  __shared__ float tile[32][33];
  const int b = blockIdx.z;
  const int n0 = blockIdx.x * 32, c0 = blockIdx.y * 32;
  const int tx = threadIdx.x, ty = threadIdx.y;
#pragma unroll
  for (int r = 0; r < 4; ++r)
    tile[ty + r * 8][tx] = feat[((size_t)b * NC + c0 + ty + r * 8) * NN + n0 + tx];
  __syncthreads();
#pragma unroll
  for (int r = 0; r < 4; ++r)
    featT[((size_t)b * NN + n0 + ty + r * 8) * NC + c0 + tx] = tile[tx][ty + r * 8];
}

// ---------------------------------------------------------------------------
// Fused gather + MLP(64,128) + maxpool + final linear, one block per center.
// ---------------------------------------------------------------------------
#define HS 36
__global__ __launch_bounds__(256) void mlp_kernel(
    const float* __restrict__ xyz, const float* __restrict__ fsrc,
    const float* __restrict__ newxyz, const int* __restrict__ bidx,
    const float* __restrict__ w1t, const float* __restrict__ b1,
    const float* __restrict__ w2t, const float* __restrict__ b2,
    const float* __restrict__ wsat, const float* __restrict__ bsa,
    float* __restrict__ out1, int useT) {
  __shared__ float h[CIN * HS];
  __shared__ float h1[NH1 * HS];
  __shared__ float pl[256];
  __shared__ float pooled[NH2];
  __shared__ int sidx[NSAMP];
  __shared__ float sc[3];
  const int cid = blockIdx.x;
  const int b = cid >> 11;
  const int s = cid & 2047;
  const int tid = threadIdx.x;
  if (tid < NSAMP) sidx[tid] = bidx[(size_t)cid * NSAMP + tid];
  if (tid < 3) sc[tid] = newxyz[(size_t)cid * 3 + tid];
  __syncthreads();
  {
    const int ss = tid >> 3, q = tid & 7;
    const int j = sidx[ss];
    if (useT) {
      const float4* fr = (const float4*)(fsrc + ((size_t)b * NN + j) * NC + q * 16);
#pragma unroll
      for (int u = 0; u < 4; ++u) {
        float4 v = fr[u];
        int c = 3 + q * 16 + u * 4;
        h[(c + 0) * HS + ss] = v.x;
        h[(c + 1) * HS + ss] = v.y;
        h[(c + 2) * HS + ss] = v.z;
        h[(c + 3) * HS + ss] = v.w;
      }
    } else {
      for (int u = 0; u < 16; ++u) {
        int c = q * 16 + u;
        h[(3 + c) * HS + ss] = fsrc[((size_t)b * NC + c) * NN + j];
      }
    }
    if (q == 0) {
      const float* pr = xyz + ((size_t)b * NN + j) * 3;
      h[0 * HS + ss] = pr[0] - sc[0];
      h[1 * HS + ss] = pr[1] - sc[1];
      h[2 * HS + ss] = pr[2] - sc[2];
    }
  }
  __syncthreads();
  {
    const int o = tid & 63, sg = tid >> 6;
    float acc[8];
    const float bb = b1[o];
#pragma unroll
    for (int i = 0; i < 8; ++i) acc[i] = bb;
    const float4* hb = (const float4*)&h[sg * 8];
    for (int k = 0; k < CIN; ++k) {
      float w = w1t[k * NH1 + o];
      float4 a = hb[k * (HS / 4) + 0];
      float4 c = hb[k * (HS / 4) + 1];
      acc[0] = fmaf(w, a.x, acc[0]); acc[1] = fmaf(w, a.y, acc[1]);
      acc[2] = fmaf(w, a.z, acc[2]); acc[3] = fmaf(w, a.w, acc[3]);
      acc[4] = fmaf(w, c.x, acc[4]); acc[5] = fmaf(w, c.y, acc[5]);
      acc[6] = fmaf(w, c.z, acc[6]); acc[7] = fmaf(w, c.w, acc[7]);
    }
#pragma unroll
    for (int i = 0; i < 8; ++i) h1[o * HS + sg * 8 + i] = fmaxf(acc[i], 0.0f);
  }
  __syncthreads();
  {
    const int o = tid & 127, sg = tid >> 7;
    float acc[16];
    const float bb = b2[o];
#pragma unroll
    for (int i = 0; i < 16; ++i) acc[i] = bb;
    const float4* hb = (const float4*)&h1[sg * 16];
    for (int k = 0; k < NH1; ++k) {
      float w = w2t[k * NH2 + o];
#pragma unroll
      for (int u = 0; u < 4; ++u) {
        float4 a = hb[k * (HS / 4) + u];
        acc[u * 4 + 0] = fmaf(w, a.x, acc[u * 4 + 0]);
        acc[u * 4 + 1] = fmaf(w, a.y, acc[u * 4 + 1]);
        acc[u * 4 + 2] = fmaf(w, a.z, acc[u * 4 + 2]);
        acc[u * 4 + 3] = fmaf(w, a.w, acc[u * 4 + 3]);
      }
    }
    float pm = acc[0];
#pragma unroll
    for (int i = 1; i < 16; ++i) pm = fmaxf(pm, acc[i]);
    pl[sg * 128 + o] = pm;
  }
  __syncthreads();
  if (tid < NH2) pooled[tid] = fmaxf(fmaxf(pl[tid], pl[128 + tid]), 0.0f);
  __syncthreads();
  if (tid < NOUTC) {
    float acc = bsa[tid];
    for (int k = 0; k < NH2; ++k) acc = fmaf(pooled[k], wsat[k * NOUTC + tid], acc);
    out1[((size_t)b * NOUTC + tid) * NPTS + s] = acc;
  }
}

extern "C" void kernel_launch(void* const* d_in, const int* in_sizes, int n_in,
                              void* d_out, int out_size, void* d_ws, size_t ws_size,
                              hipStream_t stream) {
  const float* xyz = (const float*)d_in[0];
  const float* feat = (const float*)d_in[1];
  const float* W1 = (const float*)d_in[2];
  const float* b1 = (const float*)d_in[3];
  const float* W2 = (const float*)d_in[4];
  const float* b2 = (const float*)d_in[5];
  const float* Wsa = (const float*)d_in[6];
  const float* bsa = (const float*)d_in[7];
  float* out = (float*)d_out;
  float* newxyz = out;                       // (B, NPTS, 3)
  float* out1 = out + (size_t)NB * NPTS * 3; // (B, OUT, NPTS)

  const size_t sort_f = (size_t)NB * NN * 4;  // xs, ys, zs, io
  const size_t small_f = (size_t)CIN * NH1 + NH1 * NH2 + NH2 * NOUTC +
                         (size_t)NB * NPTS * NSAMP;
  const size_t featT_f = (size_t)NB * NN * NC;

  float* ws = (float*)d_ws;
  bool useSort = ws_size >= (sort_f + small_f) * 4;
  bool useT = ws_size >= (sort_f + small_f + featT_f) * 4;

  float* xs = ws;
  float* ysr = xs + (size_t)NB * NN;
  float* zsr = ysr + (size_t)NB * NN;
  int* iosr = (int*)(zsr + (size_t)NB * NN);
  float* base2 = useSort ? (ws + sort_f) : ws;
  float* w1t = base2;
  float* w2t = w1t + CIN * NH1;
  float* wsat = w2t + NH1 * NH2;
  int* bidx = (int*)(wsat + NH2 * NOUTC);
  float* featT = (float*)(bidx + (size_t)NB * NPTS * NSAMP);

  tw_kernel<<<64, 256, 0, stream>>>(W1, W2, Wsa, w1t, w2t, wsat);
  if (useT)
    tfeat_kernel<<<dim3(NN / 32, NC / 32, NB), dim3(32, 8), 0, stream>>>(feat, featT);
  if (useSort) {
    sort_kernel<<<NB, 1024, 0, stream>>>(xyz, xs, ysr, zsr, iosr);
    fps_kernel<<<NB, 1024, 0, stream>>>(xyz, xs, ysr, zsr, iosr, newxyz);
  } else {
    fps_nosort_kernel<<<NB, 1024, 0, stream>>>(xyz, newxyz);
  }
  ballq_kernel<<<NB * NPTS / 4, 256, 0, stream>>>(xyz, newxyz, bidx);
  mlp_kernel<<<NB * NPTS, 256, 0, stream>>>(xyz, useT ? featT : feat, newxyz, bidx,
                                            w1t, b1, w2t, b2, wsat, bsa, out1,
                                            (int)useT);
}

// Round 9
// 3679.423 us; speedup vs baseline: 1.1624x; 1.0432x over previous
//
#include <hip/hip_runtime.h>
#include <cstdint>
#include <cstddef>

#define NB 4
#define NN 8192
#define NPTS 2048
#define NSAMP 32
#define NC 128
#define CIN 131      // 3 + NC
#define NH1 64
#define NH2 128
#define NOUTC 128
#define GCELLS 4096  // 16x16x16 morton grid

typedef float v2f __attribute__((ext_vector_type(2)));
typedef unsigned long long ull;

// Exact (numpy-order, contraction-free) squared distance:
// ((dx*dx + dy*dy) + dz*dz), round-to-nearest each op, no FMA.
__device__ __forceinline__ float d2_exact(float ax, float ay, float az,
                                          float bx, float by, float bz) {
  float dx = ax - bx, dy = ay - by, dz = az - bz;
  return __fadd_rn(__fadd_rn(__fmul_rn(dx, dx), __fmul_rn(dy, dy)),
                   __fmul_rn(dz, dz));
}

// ---- DPP cross-lane (VALU, no LDS). 0xB1=xor1 0x4E=xor2 0x141=half-mirror
// (xor7) 0x140=row-mirror (xor15). {1,2,7,15} spans a 16-lane butterfly;
// +shfl_xor 16/32 extends to the full wave. (Validated exact in R2-R8.)
#if __has_builtin(__builtin_amdgcn_mov_dpp)
template <int CTRL>
__device__ __forceinline__ float dppf(float v) {
  return __int_as_float(
      __builtin_amdgcn_mov_dpp(__float_as_int(v), CTRL, 0xF, 0xF, true));
}
template <int CTRL>
__device__ __forceinline__ int dppi(int v) {
  return __builtin_amdgcn_mov_dpp(v, CTRL, 0xF, 0xF, true);
}
#else
template <int CTRL>
__device__ __forceinline__ float dppf(float v) {
  const int m = (CTRL == 0xB1) ? 1 : (CTRL == 0x4E) ? 2 : (CTRL == 0x141) ? 7 : 15;
  return __shfl_xor(v, m);
}
template <int CTRL>
__device__ __forceinline__ int dppi(int v) {
  const int m = (CTRL == 0xB1) ? 1 : (CTRL == 0x4E) ? 2 : (CTRL == 0x141) ? 7 : 15;
  return __shfl_xor(v, m);
}
#endif

// 64-bit key = (d2_bits << 32) | ~orig_idx. d2 >= +0.0 always (sums of
// squares, RN), so float bit order == numeric order; larger ~idx == smaller
// idx. u64 max == (dist desc, orig idx asc) == np.argmax semantics, exactly.
template <int CTRL>
__device__ __forceinline__ ull dppk(ull k) {
  int hi = dppi<CTRL>((int)(k >> 32));
  int lo = dppi<CTRL>((int)(unsigned)k);
  return ((ull)(unsigned)hi << 32) | (unsigned)lo;
}
__device__ __forceinline__ ull shflk(ull k, int m) {
  int hi = __shfl_xor((int)(k >> 32), m);
  int lo = __shfl_xor((int)(unsigned)k, m);
  return ((ull)(unsigned)hi << 32) | (unsigned)lo;
}

// key+coords merge level via DPP (16-slot cross-wave merge)
template <int CTRL>
__device__ __forceinline__ void redk5(ull& k, float& x, float& y, float& z) {
  ull ok = dppk<CTRL>(k);
  float ox = dppf<CTRL>(x), oy = dppf<CTRL>(y), oz = dppf<CTRL>(z);
  bool t = ok > k;
  k = t ? ok : k;
  x = t ? ox : x;
  y = t ? oy : y;
  z = t ? oz : z;
}

// argmax combine for (v,i) pairs (fallback kernel only)
__device__ __forceinline__ void red_pair(float& bv, int& bi, float ov, int oi) {
  bool t = (ov > bv) || (ov == bv && oi < bi);
  bv = t ? ov : bv;
  bi = t ? oi : bi;
}

// v2f-array 8->1 select tree, compile-time friendly (k = 2*p + comp)
#define SEL8V(A, kk, out)                     \
  {                                           \
    v2f t0_ = ((kk) & 2) ? A[1] : A[0];       \
    v2f t1_ = ((kk) & 2) ? A[3] : A[2];       \
    v2f t2_ = ((kk) & 4) ? t1_ : t0_;         \
    out = ((kk) & 1) ? t2_.y : t2_.x;         \
  }

// ---------------------------------------------------------------------------
// Spatial counting sort into 16^3 morton cells (one block per batch).
// Order within a cell is nondeterministic (LDS atomics) — harmless: FPS
// selection is order-independent (u64 keys form a total order).
// ---------------------------------------------------------------------------
__device__ __forceinline__ int spread3(int v) {  // 4 bits -> every 3rd bit
  return (v & 1) | ((v & 2) << 2) | ((v & 4) << 4) | ((v & 8) << 6);
}

__global__ __launch_bounds__(1024, 1) void sort_kernel(
    const float* __restrict__ xyz, float* __restrict__ xs,
    float* __restrict__ ys, float* __restrict__ zs, int* __restrict__ io) {
  __shared__ int hist[GCELLS];
  __shared__ int cbase[GCELLS];
  __shared__ int wtot[16];
  __shared__ int woff[16];
  const int b = blockIdx.x;
  const int tid = threadIdx.x;
  const int lane = tid & 63;
  const int wid = tid >> 6;
  const float* xb = xyz + (size_t)b * NN * 3;
  for (int i = tid; i < GCELLS; i += 1024) hist[i] = 0;
  __syncthreads();
  int cell[8];
  float px[8], py[8], pz[8];
#pragma unroll
  for (int k = 0; k < 8; ++k) {
    int j = tid + (k << 10);
    float x = xb[j * 3 + 0], y = xb[j * 3 + 1], z = xb[j * 3 + 2];
    px[k] = x; py[k] = y; pz[k] = z;
    int cx = min(15, max(0, (int)(x * 16.0f)));
    int cy = min(15, max(0, (int)(y * 16.0f)));
    int cz = min(15, max(0, (int)(z * 16.0f)));
    cell[k] = spread3(cx) | (spread3(cy) << 1) | (spread3(cz) << 2);
    atomicAdd(&hist[cell[k]], 1);
  }
  __syncthreads();
  const int i0 = tid * 4;
  int h0 = hist[i0], h1 = hist[i0 + 1], h2 = hist[i0 + 2], h3 = hist[i0 + 3];
  int s4 = h0 + h1 + h2 + h3;
  int v = s4;
#pragma unroll
  for (int d = 1; d < 64; d <<= 1) {
    int o = __shfl_up(v, d);
    if (lane >= d) v += o;
  }
  if (lane == 63) wtot[wid] = v;
  __syncthreads();
  if (tid < 16) {
    int acc = 0;
    for (int w = 0; w < 16; ++w) {
      if (w == tid) woff[tid] = acc;
      acc += wtot[w];
    }
  }
  __syncthreads();
  int eb = woff[wid] + v - s4;
  cbase[i0] = eb;
  cbase[i0 + 1] = eb + h0;
  cbase[i0 + 2] = eb + h0 + h1;
  cbase[i0 + 3] = eb + h0 + h1 + h2;
  __syncthreads();
  for (int i = tid; i < GCELLS; i += 1024) hist[i] = 0;
  __syncthreads();
  const size_t bo = (size_t)b * NN;
#pragma unroll
  for (int k = 0; k < 8; ++k) {
    int pos = cbase[cell[k]] + atomicAdd(&hist[cell[k]], 1);
    xs[bo + pos] = px[k];
    ys[bo + pos] = py[k];
    zs[bo + pos] = pz[k];
    io[bo + pos] = tid + (k << 10);
  }
}

// ---------------------------------------------------------------------------
// FPS v7: R6 skeleton (single barrier, parity slots, all-wave redundant
// merge — best measured structure) with an instruction diet:
//  - packed v2f d2+min (v_pk_* f32; per-op RN, contract(off) -> bit-exact)
//  - u64-key argmax tracking/reduction (1 cmp_u64 per combine instead of the
//    5-7 op (value,idx) comparator chain); key order == np.argmax semantics.
//  - tid 0 writes newxyz from merged registers.
// ---------------------------------------------------------------------------
__global__ __launch_bounds__(1024, 1) void fps_kernel(
    const float* __restrict__ xyz, const float* __restrict__ xs,
    const float* __restrict__ ys, const float* __restrict__ zs,
    const int* __restrict__ io, float* __restrict__ newxyz) {
#pragma clang fp contract(off)
  const int b = blockIdx.x;
  const int tid = threadIdx.x;
  const int lane = tid & 63;
  const int wid = tid >> 6;
  const size_t bo = (size_t)b * NN;

  v2f X2[4], Y2[4], Z2[4], D2[4];
  unsigned invI[8];
#pragma unroll
  for (int p = 0; p < 4; ++p) {
    int s0 = tid * 8 + 2 * p, s1 = s0 + 1;
    X2[p].x = xs[bo + s0]; X2[p].y = xs[bo + s1];
    Y2[p].x = ys[bo + s0]; Y2[p].y = ys[bo + s1];
    Z2[p].x = zs[bo + s0]; Z2[p].y = zs[bo + s1];
    invI[2 * p] = ~(unsigned)io[bo + s0];
    invI[2 * p + 1] = ~(unsigned)io[bo + s1];
    D2[p].x = 1e30f;  // any init > 3 gives bitwise-identical first min
    D2[p].y = 1e30f;
  }

  __shared__ int skh[2][16], skl[2][16];
  __shared__ float sx[2][16], sy[2][16], sz[2][16];

  const float* xb = xyz + (size_t)b * NN * 3;
  float cx = xb[0], cy = xb[1], cz = xb[2];
  if (tid == 0) {
    newxyz[(size_t)b * NPTS * 3 + 0] = cx;
    newxyz[(size_t)b * NPTS * 3 + 1] = cy;
    newxyz[(size_t)b * NPTS * 3 + 2] = cz;
  }

  for (int t = 1; t < NPTS; ++t) {
    const int par = t & 1;
    const v2f cxv = {cx, cx}, cyv = {cy, cy}, czv = {cz, cz};
    // ---- body: packed update, u64-key best tracking ----
    ull bkey = 0ull;
    int kw = 0;
#pragma unroll
    for (int p = 0; p < 4; ++p) {
      v2f dx = X2[p] - cxv;
      v2f dy = Y2[p] - cyv;
      v2f dz = Z2[p] - czv;
      v2f s = dx * dx + dy * dy + dz * dz;  // ((xx+yy)+zz), each op RN
      v2f nd;
      nd.x = fminf(D2[p].x, s.x);
      nd.y = fminf(D2[p].y, s.y);
      D2[p] = nd;
      ull k0 = ((ull)__float_as_uint(nd.x) << 32) | invI[2 * p];
      bool c0 = k0 > bkey;
      bkey = c0 ? k0 : bkey;
      kw = c0 ? (2 * p) : kw;
      ull k1 = ((ull)__float_as_uint(nd.y) << 32) | invI[2 * p + 1];
      bool c1 = k1 > bkey;
      bkey = c1 ? k1 : bkey;
      kw = c1 ? (2 * p + 1) : kw;
    }
    // ---- wave allreduce (u64 max) ----
    ull rk = bkey;
    { ull o = dppk<0xB1>(rk);  rk = o > rk ? o : rk; }
    { ull o = dppk<0x4E>(rk);  rk = o > rk ? o : rk; }
    { ull o = dppk<0x141>(rk); rk = o > rk ? o : rk; }
    { ull o = dppk<0x140>(rk); rk = o > rk ? o : rk; }
    { ull o = shflk(rk, 16);   rk = o > rk ? o : rk; }
    { ull o = shflk(rk, 32);   rk = o > rk ? o : rk; }
    // ---- unique owner lane publishes its wave's entry (keys are unique) ----
    if (bkey == rk) {
      float ox, oy, oz;
      SEL8V(X2, kw, ox);
      SEL8V(Y2, kw, oy);
      SEL8V(Z2, kw, oz);
      skh[par][wid] = (int)(rk >> 32);
      skl[par][wid] = (int)(unsigned)rk;
      sx[par][wid] = ox;
      sy[par][wid] = oy;
      sz[par][wid] = oz;
    }
    __syncthreads();  // one barrier/step (parity slots; reuse at t+2 is
                      // ordered by the t+1 barrier)
    // ---- 16-slot merge, all threads (row-local DPP, keys + coords) ----
    const int sl = lane & 15;
    ull mk = ((ull)(unsigned)skh[par][sl] << 32) | (unsigned)skl[par][sl];
    float xx = sx[par][sl], yy = sy[par][sl], zz = sz[par][sl];
    redk5<0xB1>(mk, xx, yy, zz);
    redk5<0x4E>(mk, xx, yy, zz);
    redk5<0x141>(mk, xx, yy, zz);
    redk5<0x140>(mk, xx, yy, zz);
    cx = xx;
    cy = yy;
    cz = zz;
    if (tid == 0) {
      size_t o = ((size_t)b * NPTS + t) * 3;
      newxyz[o + 0] = xx;
      newxyz[o + 1] = yy;
      newxyz[o + 2] = zz;
    }
  }
}

// ---------------------------------------------------------------------------
// Fallback FPS (no workspace): R2's 1024-thread register kernel.
// ---------------------------------------------------------------------------
__global__ __launch_bounds__(1024, 1) void fps_nosort_kernel(
    const float* __restrict__ xyz, float* __restrict__ newxyz) {
#pragma clang fp contract(off)
  const int b = blockIdx.x;
  const int tid = threadIdx.x;
  const int lane = tid & 63;
  const int wid = tid >> 6;
  const float* xb = xyz + (size_t)b * NN * 3;
  v2f x2[4], y2[4], z2[4], dd[4];
#pragma unroll
  for (int p = 0; p < 4; ++p) {
    int j0 = tid + ((2 * p) << 10);
    int j1 = tid + ((2 * p + 1) << 10);
    x2[p].x = xb[j0 * 3 + 0]; x2[p].y = xb[j1 * 3 + 0];
    y2[p].x = xb[j0 * 3 + 1]; y2[p].y = xb[j1 * 3 + 1];
    z2[p].x = xb[j0 * 3 + 2]; z2[p].y = xb[j1 * 3 + 2];
    dd[p].x = 1e10f; dd[p].y = 1e10f;
  }
  __shared__ float vbuf[2][16];
  __shared__ int ibuf[2][16];
  __shared__ float cbuf[2][16][3];
  float cx = xb[0], cy = xb[1], cz = xb[2];
  if (tid == 0) {
    newxyz[(size_t)b * NPTS * 3 + 0] = cx;
    newxyz[(size_t)b * NPTS * 3 + 1] = cy;
    newxyz[(size_t)b * NPTS * 3 + 2] = cz;
  }
  for (int t = 1; t < NPTS; ++t) {
    const int par = t & 1;
    float bv = -1.0f; int bi = 0;
    float bwx = 0.f, bwy = 0.f, bwz = 0.f;
#pragma unroll
    for (int p = 0; p < 4; ++p) {
      v2f dx = x2[p] - (v2f){cx, cx};
      v2f dy = y2[p] - (v2f){cy, cy};
      v2f dz = z2[p] - (v2f){cz, cz};
      v2f s = dx * dx + dy * dy + dz * dz;
      v2f nd;
      nd.x = fminf(dd[p].x, s.x);
      nd.y = fminf(dd[p].y, s.y);
      dd[p] = nd;
      { bool c = nd.x > bv;
        bv = c ? nd.x : bv; bi = c ? (tid + ((2 * p) << 10)) : bi;
        bwx = c ? x2[p].x : bwx; bwy = c ? y2[p].x : bwy; bwz = c ? z2[p].x : bwz; }
      { bool c = nd.y > bv;
        bv = c ? nd.y : bv; bi = c ? (tid + ((2 * p + 1) << 10)) : bi;
        bwx = c ? x2[p].y : bwx; bwy = c ? y2[p].y : bwy; bwz = c ? z2[p].y : bwz; }
    }
    red_pair(bv, bi, dppf<0xB1>(bv), dppi<0xB1>(bi));
    red_pair(bv, bi, dppf<0x4E>(bv), dppi<0x4E>(bi));
    red_pair(bv, bi, dppf<0x141>(bv), dppi<0x141>(bi));
    red_pair(bv, bi, dppf<0x140>(bv), dppi<0x140>(bi));
    red_pair(bv, bi, __shfl_xor(bv, 16), __shfl_xor(bi, 16));
    red_pair(bv, bi, __shfl_xor(bv, 32), __shfl_xor(bi, 32));
    if (tid == (bi & 1023)) {
      vbuf[par][wid] = bv; ibuf[par][wid] = bi;
      cbuf[par][wid][0] = bwx; cbuf[par][wid][1] = bwy; cbuf[par][wid][2] = bwz;
    }
    __syncthreads();
    float v2w = vbuf[par][lane & 15];
    int i2w = ibuf[par][lane & 15];
    red_pair(v2w, i2w, dppf<0xB1>(v2w), dppi<0xB1>(i2w));
    red_pair(v2w, i2w, dppf<0x4E>(v2w), dppi<0x4E>(i2w));
    red_pair(v2w, i2w, dppf<0x141>(v2w), dppi<0x141>(i2w));
    red_pair(v2w, i2w, dppf<0x140>(v2w), dppi<0x140>(i2w));
    const int slot = (i2w & 1023) >> 6;
    cx = cbuf[par][slot][0]; cy = cbuf[par][slot][1]; cz = cbuf[par][slot][2];
    if (tid == (i2w & 1023)) {
      size_t o = ((size_t)b * NPTS + t) * 3;
      newxyz[o + 0] = cx; newxyz[o + 1] = cy; newxyz[o + 2] = cz;
    }
  }
}

// ---------------------------------------------------------------------------
// Ball query: one wave per center; ballot scan in index order -> first 32 hits.
// ---------------------------------------------------------------------------
__global__ __launch_bounds__(256) void ballq_kernel(
    const float* __restrict__ xyz, const float* __restrict__ newxyz,
    int* __restrict__ bidx) {
  const int cid = blockIdx.x * 4 + (threadIdx.x >> 6);
  const int lane = threadIdx.x & 63;
  const int b = cid >> 11;
  const float* xb = xyz + (size_t)b * NN * 3;
  const float cx = newxyz[(size_t)cid * 3 + 0];
  const float cy = newxyz[(size_t)cid * 3 + 1];
  const float cz = newxyz[(size_t)cid * 3 + 2];
  int* ob = bidx + (size_t)cid * NSAMP;
  int total = 0;
  int first = -1;
  for (int c0 = 0; c0 < NN; c0 += 64) {
    int j = c0 + lane;
    float xx = xb[j * 3 + 0], yy = xb[j * 3 + 1], zz = xb[j * 3 + 2];
    float d2 = d2_exact(cx, cy, cz, xx, yy, zz);
    bool in = d2 <= 0.04f;
    unsigned long long m = __ballot(in);
    if (first < 0 && m) first = c0 + __builtin_ctzll(m);
    int pos = total + __popcll(m & ((1ull << lane) - 1ull));
    if (in && pos < NSAMP) ob[pos] = j;
    total += __popcll(m);
    if (total >= NSAMP) break;
  }
  if (total < NSAMP && lane < NSAMP - total) ob[total + lane] = first;
}

// ---------------------------------------------------------------------------
__global__ void tw_kernel(const float* __restrict__ W1, const float* __restrict__ W2,
                          const float* __restrict__ Wsa, float* __restrict__ w1t,
                          float* __restrict__ w2t, float* __restrict__ wsat) {
  int i = blockIdx.x * blockDim.x + threadIdx.x;
  if (i < CIN * NH1) w1t[i] = W1[(i % NH1) * CIN + (i / NH1)];
  if (i < NH1 * NH2) w2t[i] = W2[(i % NH2) * NH1 + (i / NH2)];
  if (i < NH2 * NOUTC) wsat[i] = Wsa[(i % NOUTC) * NH2 + (i / NOUTC)];
}

__global__ void tfeat_kernel(const float* __restrict__ feat, float* __restrict__ featT) {
  __shared__ float tile[32][33];
  const int b = blockIdx.z;
  const int n0 = blockIdx.x * 32, c0 = blockIdx.y * 32;
  const int tx = threadIdx.x, ty = threadIdx.y;
#pragma unroll
  for (int r = 0; r < 4; ++r)
    tile[ty + r * 8][tx] = feat[((size_t)b * NC + c0 + ty + r * 8) * NN + n0 + tx];
  __syncthreads();
#pragma unroll
  for (int r = 0; r < 4; ++r)
    featT[((size_t)b * NN + n0 + ty + r * 8) * NC + c0 + tx] = tile[tx][ty + r * 8];
}

// ---------------------------------------------------------------------------
// Fused gather + MLP(64,128) + maxpool + final linear, one block per center.
// ---------------------------------------------------------------------------
#define HS 36
__global__ __launch_bounds__(256) void mlp_kernel(
    const float* __restrict__ xyz, const float* __restrict__ fsrc,
    const float* __restrict__ newxyz, const int* __restrict__ bidx,
    const float* __restrict__ w1t, const float* __restrict__ b1,
    const float* __restrict__ w2t, const float* __restrict__ b2,
    const float* __restrict__ wsat, const float* __restrict__ bsa,
    float* __restrict__ out1, int useT) {
  __shared__ float h[CIN * HS];
  __shared__ float h1[NH1 * HS];
  __shared__ float pl[256];
  __shared__ float pooled[NH2];
  __shared__ int sidx[NSAMP];
  __shared__ float sc[3];
  const int cid = blockIdx.x;
  const int b = cid >> 11;
  const int s = cid & 2047;
  const int tid = threadIdx.x;
  if (tid < NSAMP) sidx[tid] = bidx[(size_t)cid * NSAMP + tid];
  if (tid < 3) sc[tid] = newxyz[(size_t)cid * 3 + tid];
  __syncthreads();
  {
    const int ss = tid >> 3, q = tid & 7;
    const int j = sidx[ss];
    if (useT) {
      const float4* fr = (const float4*)(fsrc + ((size_t)b * NN + j) * NC + q * 16);
#pragma unroll
      for (int u = 0; u < 4; ++u) {
        float4 v = fr[u];
        int c = 3 + q * 16 + u * 4;
        h[(c + 0) * HS + ss] = v.x;
        h[(c + 1) * HS + ss] = v.y;
        h[(c + 2) * HS + ss] = v.z;
        h[(c + 3) * HS + ss] = v.w;
      }
    } else {
      for (int u = 0; u < 16; ++u) {
        int c = q * 16 + u;
        h[(3 + c) * HS + ss] = fsrc[((size_t)b * NC + c) * NN + j];
      }
    }
    if (q == 0) {
      const float* pr = xyz + ((size_t)b * NN + j) * 3;
      h[0 * HS + ss] = pr[0] - sc[0];
      h[1 * HS + ss] = pr[1] - sc[1];
      h[2 * HS + ss] = pr[2] - sc[2];
    }
  }
  __syncthreads();
  {
    const int o = tid & 63, sg = tid >> 6;
    float acc[8];
    const float bb = b1[o];
#pragma unroll
    for (int i = 0; i < 8; ++i) acc[i] = bb;
    const float4* hb = (const float4*)&h[sg * 8];
    for (int k = 0; k < CIN; ++k) {
      float w = w1t[k * NH1 + o];
      float4 a = hb[k * (HS / 4) + 0];
      float4 c = hb[k * (HS / 4) + 1];
      acc[0] = fmaf(w, a.x, acc[0]); acc[1] = fmaf(w, a.y, acc[1]);
      acc[2] = fmaf(w, a.z, acc[2]); acc[3] = fmaf(w, a.w, acc[3]);
      acc[4] = fmaf(w, c.x, acc[4]); acc[5] = fmaf(w, c.y, acc[5]);
      acc[6] = fmaf(w, c.z, acc[6]); acc[7] = fmaf(w, c.w, acc[7]);
    }
#pragma unroll
    for (int i = 0; i < 8; ++i) h1[o * HS + sg * 8 + i] = fmaxf(acc[i], 0.0f);
  }
  __syncthreads();
  {
    const int o = tid & 127, sg = tid >> 7;
    float acc[16];
    const float bb = b2[o];
#pragma unroll
    for (int i = 0; i < 16; ++i) acc[i] = bb;
    const float4* hb = (const float4*)&h1[sg * 16];
    for (int k = 0; k < NH1; ++k) {
      float w = w2t[k * NH2 + o];
#pragma unroll
      for (int u = 0; u < 4; ++u) {
        float4 a = hb[k * (HS / 4) + u];
        acc[u * 4 + 0] = fmaf(w, a.x, acc[u * 4 + 0]);
        acc[u * 4 + 1] = fmaf(w, a.y, acc[u * 4 + 1]);
        acc[u * 4 + 2] = fmaf(w, a.z, acc[u * 4 + 2]);
        acc[u * 4 + 3] = fmaf(w, a.w, acc[u * 4 + 3]);
      }
    }
    float pm = acc[0];
#pragma unroll
    for (int i = 1; i < 16; ++i) pm = fmaxf(pm, acc[i]);
    pl[sg * 128 + o] = pm;
  }
  __syncthreads();
  if (tid < NH2) pooled[tid] = fmaxf(fmaxf(pl[tid], pl[128 + tid]), 0.0f);
  __syncthreads();
  if (tid < NOUTC) {
    float acc = bsa[tid];
    for (int k = 0; k < NH2; ++k) acc = fmaf(pooled[k], wsat[k * NOUTC + tid], acc);
    out1[((size_t)b * NOUTC + tid) * NPTS + s] = acc;
  }
}

extern "C" void kernel_launch(void* const* d_in, const int* in_sizes, int n_in,
                              void* d_out, int out_size, void* d_ws, size_t ws_size,
                              hipStream_t stream) {
  const float* xyz = (const float*)d_in[0];
  const float* feat = (const float*)d_in[1];
  const float* W1 = (const float*)d_in[2];
  const float* b1 = (const float*)d_in[3];
  const float* W2 = (const float*)d_in[4];
  const float* b2 = (const float*)d_in[5];
  const float* Wsa = (const float*)d_in[6];
  const float* bsa = (const float*)d_in[7];
  float* out = (float*)d_out;
  float* newxyz = out;                       // (B, NPTS, 3)
  float* out1 = out + (size_t)NB * NPTS * 3; // (B, OUT, NPTS)

  const size_t sort_f = (size_t)NB * NN * 4;  // xs, ys, zs, io
  const size_t small_f = (size_t)CIN * NH1 + NH1 * NH2 + NH2 * NOUTC +
                         (size_t)NB * NPTS * NSAMP;
  const size_t featT_f = (size_t)NB * NN * NC;

  float* ws = (float*)d_ws;
  bool useSort = ws_size >= (sort_f + small_f) * 4;
  bool useT = ws_size >= (sort_f + small_f + featT_f) * 4;

  float* xs = ws;
  float* ysr = xs + (size_t)NB * NN;
  float* zsr = ysr + (size_t)NB * NN;
  int* iosr = (int*)(zsr + (size_t)NB * NN);
  float* base2 = useSort ? (ws + sort_f) : ws;
  float* w1t = base2;
  float* w2t = w1t + CIN * NH1;
  float* wsat = w2t + NH1 * NH2;
  int* bidx = (int*)(wsat + NH2 * NOUTC);
  float* featT = (float*)(bidx + (size_t)NB * NPTS * NSAMP);

  tw_kernel<<<64, 256, 0, stream>>>(W1, W2, Wsa, w1t, w2t, wsat);
  if (useT)
    tfeat_kernel<<<dim3(NN / 32, NC / 32, NB), dim3(32, 8), 0, stream>>>(feat, featT);
  if (useSort) {
    sort_kernel<<<NB, 1024, 0, stream>>>(xyz, xs, ysr, zsr, iosr);
    fps_kernel<<<NB, 1024, 0, stream>>>(xyz, xs, ysr, zsr, iosr, newxyz);
  } else {
    fps_nosort_kernel<<<NB, 1024, 0, stream>>>(xyz, newxyz);
  }
  ballq_kernel<<<NB * NPTS / 4, 256, 0, stream>>>(xyz, newxyz, bidx);
  mlp_kernel<<<NB * NPTS, 256, 0, stream>>>(xyz, useT ? featT : feat, newxyz, bidx,
                                            w1t, b1, w2t, b2, wsat, bsa, out1,
                                            (int)useT);
}

// Round 10
// 3661.831 us; speedup vs baseline: 1.1680x; 1.0048x over previous
//
#include <hip/hip_runtime.h>
#include <cstdint>
#include <cstddef>

#define NB 4
#define NN 8192
#define NPTS 2048
#define NSAMP 32
#define NC 128
#define CIN 131      // 3 + NC
#define NH1 64
#define NH2 128
#define NOUTC 128
#define GCELLS 4096  // 16x16x16 morton grid

typedef float v2f __attribute__((ext_vector_type(2)));
typedef unsigned long long ull;

// Exact (numpy-order, contraction-free) squared distance:
// ((dx*dx + dy*dy) + dz*dz), round-to-nearest each op, no FMA.
__device__ __forceinline__ float d2_exact(float ax, float ay, float az,
                                          float bx, float by, float bz) {
  float dx = ax - bx, dy = ay - by, dz = az - bz;
  return __fadd_rn(__fadd_rn(__fmul_rn(dx, dx), __fmul_rn(dy, dy)),
                   __fmul_rn(dz, dz));
}

// ---- DPP cross-lane (VALU, no LDS). 0xB1=xor1 0x4E=xor2 0x141=half-mirror
// (xor7) 0x140=row-mirror (xor15). {1,2,7} spans an 8-lane allreduce
// (xor7 flips bit2 across quads); +{15} spans 16; +shfl 16/32 the wave.
#if __has_builtin(__builtin_amdgcn_mov_dpp)
template <int CTRL>
__device__ __forceinline__ float dppf(float v) {
  return __int_as_float(
      __builtin_amdgcn_mov_dpp(__float_as_int(v), CTRL, 0xF, 0xF, true));
}
template <int CTRL>
__device__ __forceinline__ int dppi(int v) {
  return __builtin_amdgcn_mov_dpp(v, CTRL, 0xF, 0xF, true);
}
#else
template <int CTRL>
__device__ __forceinline__ float dppf(float v) {
  const int m = (CTRL == 0xB1) ? 1 : (CTRL == 0x4E) ? 2 : (CTRL == 0x141) ? 7 : 15;
  return __shfl_xor(v, m);
}
template <int CTRL>
__device__ __forceinline__ int dppi(int v) {
  const int m = (CTRL == 0xB1) ? 1 : (CTRL == 0x4E) ? 2 : (CTRL == 0x141) ? 7 : 15;
  return __shfl_xor(v, m);
}
#endif

// 64-bit key = (d2_bits << 32) | ~orig_idx. d2 >= +0.0 always (sum of squares,
// RN), so float bit order == numeric order; larger ~idx == smaller idx.
// u64 max == (dist desc, orig idx asc) == np.argmax semantics, exactly.
template <int CTRL>
__device__ __forceinline__ ull dppk(ull k) {
  int hi = dppi<CTRL>((int)(k >> 32));
  int lo = dppi<CTRL>((int)(unsigned)k);
  return ((ull)(unsigned)hi << 32) | (unsigned)lo;
}
__device__ __forceinline__ ull shflk(ull k, int m) {
  int hi = __shfl_xor((int)(k >> 32), m);
  int lo = __shfl_xor((int)(unsigned)k, m);
  return ((ull)(unsigned)hi << 32) | (unsigned)lo;
}

// key+coords merge level via DPP (8-slot cross-wave merge)
template <int CTRL>
__device__ __forceinline__ void redk5(ull& k, float& x, float& y, float& z) {
  ull ok = dppk<CTRL>(k);
  float ox = dppf<CTRL>(x), oy = dppf<CTRL>(y), oz = dppf<CTRL>(z);
  bool t = ok > k;
  k = t ? ok : k;
  x = t ? ox : x;
  y = t ? oy : y;
  z = t ? oz : z;
}

// argmax combine for (v,i) pairs (fallback kernel only)
__device__ __forceinline__ void red_pair(float& bv, int& bi, float ov, int oi) {
  bool t = (ov > bv) || (ov == bv && oi < bi);
  bv = t ? ov : bv;
  bi = t ? oi : bi;
}

// 16->1 register select tree (compile-time indices only; scratch-safe)
#define SEL16(A, kk, out)                                              \
  {                                                                    \
    float a0_ = ((kk) & 1) ? A[1] : A[0];                              \
    float a1_ = ((kk) & 1) ? A[3] : A[2];                              \
    float a2_ = ((kk) & 1) ? A[5] : A[4];                              \
    float a3_ = ((kk) & 1) ? A[7] : A[6];                              \
    float a4_ = ((kk) & 1) ? A[9] : A[8];                              \
    float a5_ = ((kk) & 1) ? A[11] : A[10];                            \
    float a6_ = ((kk) & 1) ? A[13] : A[12];                            \
    float a7_ = ((kk) & 1) ? A[15] : A[14];                            \
    float b0_ = ((kk) & 2) ? a1_ : a0_;                                \
    float b1_ = ((kk) & 2) ? a3_ : a2_;                                \
    float b2_ = ((kk) & 2) ? a5_ : a4_;                                \
    float b3_ = ((kk) & 2) ? a7_ : a6_;                                \
    float c0_ = ((kk) & 4) ? b1_ : b0_;                                \
    float c1_ = ((kk) & 4) ? b3_ : b2_;                                \
    out = ((kk) & 8) ? c1_ : c0_;                                      \
  }

// ---------------------------------------------------------------------------
// Spatial counting sort into 16^3 morton cells (one block per batch).
// Order within a cell is nondeterministic (LDS atomics) — harmless: FPS
// selection is order-independent (u64 keys form a total order).
// ---------------------------------------------------------------------------
__device__ __forceinline__ int spread3(int v) {  // 4 bits -> every 3rd bit
  return (v & 1) | ((v & 2) << 2) | ((v & 4) << 4) | ((v & 8) << 6);
}

__global__ __launch_bounds__(1024, 1) void sort_kernel(
    const float* __restrict__ xyz, float* __restrict__ xs,
    float* __restrict__ ys, float* __restrict__ zs, int* __restrict__ io) {
  __shared__ int hist[GCELLS];
  __shared__ int cbase[GCELLS];
  __shared__ int wtot[16];
  __shared__ int woff[16];
  const int b = blockIdx.x;
  const int tid = threadIdx.x;
  const int lane = tid & 63;
  const int wid = tid >> 6;
  const float* xb = xyz + (size_t)b * NN * 3;
  for (int i = tid; i < GCELLS; i += 1024) hist[i] = 0;
  __syncthreads();
  int cell[8];
  float px[8], py[8], pz[8];
#pragma unroll
  for (int k = 0; k < 8; ++k) {
    int j = tid + (k << 10);
    float x = xb[j * 3 + 0], y = xb[j * 3 + 1], z = xb[j * 3 + 2];
    px[k] = x; py[k] = y; pz[k] = z;
    int cx = min(15, max(0, (int)(x * 16.0f)));
    int cy = min(15, max(0, (int)(y * 16.0f)));
    int cz = min(15, max(0, (int)(z * 16.0f)));
    cell[k] = spread3(cx) | (spread3(cy) << 1) | (spread3(cz) << 2);
    atomicAdd(&hist[cell[k]], 1);
  }
  __syncthreads();
  const int i0 = tid * 4;
  int h0 = hist[i0], h1 = hist[i0 + 1], h2 = hist[i0 + 2], h3 = hist[i0 + 3];
  int s4 = h0 + h1 + h2 + h3;
  int v = s4;
#pragma unroll
  for (int d = 1; d < 64; d <<= 1) {
    int o = __shfl_up(v, d);
    if (lane >= d) v += o;
  }
  if (lane == 63) wtot[wid] = v;
  __syncthreads();
  if (tid < 16) {
    int acc = 0;
    for (int w = 0; w < 16; ++w) {
      if (w == tid) woff[tid] = acc;
      acc += wtot[w];
    }
  }
  __syncthreads();
  int eb = woff[wid] + v - s4;
  cbase[i0] = eb;
  cbase[i0 + 1] = eb + h0;
  cbase[i0 + 2] = eb + h0 + h1;
  cbase[i0 + 3] = eb + h0 + h1 + h2;
  __syncthreads();
  for (int i = tid; i < GCELLS; i += 1024) hist[i] = 0;
  __syncthreads();
  const size_t bo = (size_t)b * NN;
#pragma unroll
  for (int k = 0; k < 8; ++k) {
    int pos = cbase[cell[k]] + atomicAdd(&hist[cell[k]], 1);
    xs[bo + pos] = px[k];
    ys[bo + pos] = py[k];
    zs[bo + pos] = pz[k];
    io[bo + pos] = tid + (k << 10);
  }
}

// ---------------------------------------------------------------------------
// FPS v8: 512 threads/batch (8 waves — HALVES per-SIMD wave count so the
// per-wave overhead (reduce+publish+merge, ~120 instr) is issued half as
// often per SIMD), 16 pts/thread register-resident, minimal body:
// per point = d2 (8 ops, exact order) + v_min + u64-key cmp/select (ties
// exact via (d2_bits<<32)|~idx key order). Single barrier, parity slots,
// 8-slot all-thread DPP merge carrying coords.
// ---------------------------------------------------------------------------
__global__ __launch_bounds__(512, 1) void fps_kernel(
    const float* __restrict__ xyz, const float* __restrict__ xs,
    const float* __restrict__ ys, const float* __restrict__ zs,
    const int* __restrict__ io, float* __restrict__ newxyz) {
#pragma clang fp contract(off)
  const int b = blockIdx.x;
  const int tid = threadIdx.x;
  const int lane = tid & 63;
  const int wid = tid >> 6;
  const size_t bo = (size_t)b * NN;

  float X[16], Y[16], Z[16], D[16];
  unsigned invI[16];
#pragma unroll
  for (int k = 0; k < 16; ++k) {
    int s = tid * 16 + k;
    X[k] = xs[bo + s];
    Y[k] = ys[bo + s];
    Z[k] = zs[bo + s];
    invI[k] = ~(unsigned)io[bo + s];
    D[k] = 1e30f;  // any init > 3 gives bitwise-identical first min
  }

  __shared__ int skh[2][8], skl[2][8];
  __shared__ float sx[2][8], sy[2][8], sz[2][8];

  const float* xb = xyz + (size_t)b * NN * 3;
  float cx = xb[0], cy = xb[1], cz = xb[2];
  if (tid == 0) {
    newxyz[(size_t)b * NPTS * 3 + 0] = cx;
    newxyz[(size_t)b * NPTS * 3 + 1] = cy;
    newxyz[(size_t)b * NPTS * 3 + 2] = cz;
  }

  for (int t = 1; t < NPTS; ++t) {
    const int par = t & 1;
    // ---- body: update D, track best u64 key + reg slot ----
    ull bkey = 0ull;
    int kw = 0;
#pragma unroll
    for (int k = 0; k < 16; ++k) {
      float dx = X[k] - cx;
      float dy = Y[k] - cy;
      float dz = Z[k] - cz;
      float s = __fadd_rn(__fadd_rn(__fmul_rn(dx, dx), __fmul_rn(dy, dy)),
                          __fmul_rn(dz, dz));
      float nd = fminf(D[k], s);
      D[k] = nd;
      ull key = ((ull)__float_as_uint(nd) << 32) | invI[k];
      bool c = key > bkey;
      bkey = c ? key : bkey;
      kw = c ? k : kw;
    }
    // ---- wave allreduce (u64 max) ----
    ull rk = bkey;
    { ull o = dppk<0xB1>(rk);  rk = o > rk ? o : rk; }
    { ull o = dppk<0x4E>(rk);  rk = o > rk ? o : rk; }
    { ull o = dppk<0x141>(rk); rk = o > rk ? o : rk; }
    { ull o = dppk<0x140>(rk); rk = o > rk ? o : rk; }
    { ull o = shflk(rk, 16);   rk = o > rk ? o : rk; }
    { ull o = shflk(rk, 32);   rk = o > rk ? o : rk; }
    // ---- unique owner lane publishes its wave's entry (keys unique) ----
    if (bkey == rk) {
      float ox, oy, oz;
      SEL16(X, kw, ox);
      SEL16(Y, kw, oy);
      SEL16(Z, kw, oz);
      skh[par][wid] = (int)(rk >> 32);
      skl[par][wid] = (int)(unsigned)rk;
      sx[par][wid] = ox;
      sy[par][wid] = oy;
      sz[par][wid] = oz;
    }
    __syncthreads();  // one barrier/step (parity slots; reuse at t+2 is
                      // ordered by the t+1 barrier)
    // ---- 8-slot merge, all threads (3 DPP levels: xor1, xor2, xor7) ----
    const int sl = lane & 7;
    ull mk = ((ull)(unsigned)skh[par][sl] << 32) | (unsigned)skl[par][sl];
    float xx = sx[par][sl], yy = sy[par][sl], zz = sz[par][sl];
    redk5<0xB1>(mk, xx, yy, zz);
    redk5<0x4E>(mk, xx, yy, zz);
    redk5<0x141>(mk, xx, yy, zz);
    cx = xx;
    cy = yy;
    cz = zz;
    if (tid == 0) {
      size_t o = ((size_t)b * NPTS + t) * 3;
      newxyz[o + 0] = xx;
      newxyz[o + 1] = yy;
      newxyz[o + 2] = zz;
    }
  }
}

// ---------------------------------------------------------------------------
// Fallback FPS (no workspace): R2's 1024-thread register kernel.
// ---------------------------------------------------------------------------
__global__ __launch_bounds__(1024, 1) void fps_nosort_kernel(
    const float* __restrict__ xyz, float* __restrict__ newxyz) {
#pragma clang fp contract(off)
  const int b = blockIdx.x;
  const int tid = threadIdx.x;
  const int lane = tid & 63;
  const int wid = tid >> 6;
  const float* xb = xyz + (size_t)b * NN * 3;
  v2f x2[4], y2[4], z2[4], dd[4];
#pragma unroll
  for (int p = 0; p < 4; ++p) {
    int j0 = tid + ((2 * p) << 10);
    int j1 = tid + ((2 * p + 1) << 10);
    x2[p].x = xb[j0 * 3 + 0]; x2[p].y = xb[j1 * 3 + 0];
    y2[p].x = xb[j0 * 3 + 1]; y2[p].y = xb[j1 * 3 + 1];
    z2[p].x = xb[j0 * 3 + 2]; z2[p].y = xb[j1 * 3 + 2];
    dd[p].x = 1e10f; dd[p].y = 1e10f;
  }
  __shared__ float vbuf[2][16];
  __shared__ int ibuf[2][16];
  __shared__ float cbuf[2][16][3];
  float cx = xb[0], cy = xb[1], cz = xb[2];
  if (tid == 0) {
    newxyz[(size_t)b * NPTS * 3 + 0] = cx;
    newxyz[(size_t)b * NPTS * 3 + 1] = cy;
    newxyz[(size_t)b * NPTS * 3 + 2] = cz;
  }
  for (int t = 1; t < NPTS; ++t) {
    const int par = t & 1;
    float bv = -1.0f; int bi = 0;
    float bwx = 0.f, bwy = 0.f, bwz = 0.f;
#pragma unroll
    for (int p = 0; p < 4; ++p) {
      v2f dx = x2[p] - (v2f){cx, cx};
      v2f dy = y2[p] - (v2f){cy, cy};
      v2f dz = z2[p] - (v2f){cz, cz};
      v2f s = dx * dx + dy * dy + dz * dz;
      v2f nd;
      nd.x = fminf(dd[p].x, s.x);
      nd.y = fminf(dd[p].y, s.y);
      dd[p] = nd;
      { bool c = nd.x > bv;
        bv = c ? nd.x : bv; bi = c ? (tid + ((2 * p) << 10)) : bi;
        bwx = c ? x2[p].x : bwx; bwy = c ? y2[p].x : bwy; bwz = c ? z2[p].x : bwz; }
      { bool c = nd.y > bv;
        bv = c ? nd.y : bv; bi = c ? (tid + ((2 * p + 1) << 10)) : bi;
        bwx = c ? x2[p].y : bwx; bwy = c ? y2[p].y : bwy; bwz = c ? z2[p].y : bwz; }
    }
    red_pair(bv, bi, dppf<0xB1>(bv), dppi<0xB1>(bi));
    red_pair(bv, bi, dppf<0x4E>(bv), dppi<0x4E>(bi));
    red_pair(bv, bi, dppf<0x141>(bv), dppi<0x141>(bi));
    red_pair(bv, bi, dppf<0x140>(bv), dppi<0x140>(bi));
    red_pair(bv, bi, __shfl_xor(bv, 16), __shfl_xor(bi, 16));
    red_pair(bv, bi, __shfl_xor(bv, 32), __shfl_xor(bi, 32));
    if (tid == (bi & 1023)) {
      vbuf[par][wid] = bv; ibuf[par][wid] = bi;
      cbuf[par][wid][0] = bwx; cbuf[par][wid][1] = bwy; cbuf[par][wid][2] = bwz;
    }
    __syncthreads();
    float v2w = vbuf[par][lane & 15];
    int i2w = ibuf[par][lane & 15];
    red_pair(v2w, i2w, dppf<0xB1>(v2w), dppi<0xB1>(i2w));
    red_pair(v2w, i2w, dppf<0x4E>(v2w), dppi<0x4E>(i2w));
    red_pair(v2w, i2w, dppf<0x141>(v2w), dppi<0x141>(i2w));
    red_pair(v2w, i2w, dppf<0x140>(v2w), dppi<0x140>(i2w));
    const int slot = (i2w & 1023) >> 6;
    cx = cbuf[par][slot][0]; cy = cbuf[par][slot][1]; cz = cbuf[par][slot][2];
    if (tid == (i2w & 1023)) {
      size_t o = ((size_t)b * NPTS + t) * 3;
      newxyz[o + 0] = cx; newxyz[o + 1] = cy; newxyz[o + 2] = cz;
    }
  }
}

// ---------------------------------------------------------------------------
// Ball query: one wave per center; ballot scan in index order -> first 32 hits.
// ---------------------------------------------------------------------------
__global__ __launch_bounds__(256) void ballq_kernel(
    const float* __restrict__ xyz, const float* __restrict__ newxyz,
    int* __restrict__ bidx) {
  const int cid = blockIdx.x * 4 + (threadIdx.x >> 6);
  const int lane = threadIdx.x & 63;
  const int b = cid >> 11;
  const float* xb = xyz + (size_t)b * NN * 3;
  const float cx = newxyz[(size_t)cid * 3 + 0];
  const float cy = newxyz[(size_t)cid * 3 + 1];
  const float cz = newxyz[(size_t)cid * 3 + 2];
  int* ob = bidx + (size_t)cid * NSAMP;
  int total = 0;
  int first = -1;
  for (int c0 = 0; c0 < NN; c0 += 64) {
    int j = c0 + lane;
    float xx = xb[j * 3 + 0], yy = xb[j * 3 + 1], zz = xb[j * 3 + 2];
    float d2 = d2_exact(cx, cy, cz, xx, yy, zz);
    bool in = d2 <= 0.04f;
    unsigned long long m = __ballot(in);
    if (first < 0 && m) first = c0 + __builtin_ctzll(m);
    int pos = total + __popcll(m & ((1ull << lane) - 1ull));
    if (in && pos < NSAMP) ob[pos] = j;
    total += __popcll(m);
    if (total >= NSAMP) break;
  }
  if (total < NSAMP && lane < NSAMP - total) ob[total + lane] = first;
}

// ---------------------------------------------------------------------------
__global__ void tw_kernel(const float* __restrict__ W1, const float* __restrict__ W2,
                          const float* __restrict__ Wsa, float* __restrict__ w1t,
                          float* __restrict__ w2t, float* __restrict__ wsat) {
  int i = blockIdx.x * blockDim.x + threadIdx.x;
  if (i < CIN * NH1) w1t[i] = W1[(i % NH1) * CIN + (i / NH1)];
  if (i < NH1 * NH2) w2t[i] = W2[(i % NH2) * NH1 + (i / NH2)];
  if (i < NH2 * NOUTC) wsat[i] = Wsa[(i % NOUTC) * NH2 + (i / NOUTC)];
}

__global__ void tfeat_kernel(const float* __restrict__ feat, float* __restrict__ featT) {
  __shared__ float tile[32][33];
  const int b = blockIdx.z;
  const int n0 = blockIdx.x * 32, c0 = blockIdx.y * 32;
  const int tx = threadIdx.x, ty = threadIdx.y;
#pragma unroll
  for (int r = 0; r < 4; ++r)
    tile[ty + r * 8][tx] = feat[((size_t)b * NC + c0 + ty + r * 8) * NN + n0 + tx];
  __syncthreads();
#pragma unroll
  for (int r = 0; r < 4; ++r)
    featT[((size_t)b * NN + n0 + ty + r * 8) * NC + c0 + tx] = tile[tx][ty + r * 8];
}

// ---------------------------------------------------------------------------
// Fused gather + MLP(64,128) + maxpool + final linear, one block per center.
// ---------------------------------------------------------------------------
#define HS 36
__global__ __launch_bounds__(256) void mlp_kernel(
    const float* __restrict__ xyz, const float* __restrict__ fsrc,
    const float* __restrict__ newxyz, const int* __restrict__ bidx,
    const float* __restrict__ w1t, const float* __restrict__ b1,
    const float* __restrict__ w2t, const float* __restrict__ b2,
    const float* __restrict__ wsat, const float* __restrict__ bsa,
    float* __restrict__ out1, int useT) {
  __shared__ float h[CIN * HS];
  __shared__ float h1[NH1 * HS];
  __shared__ float pl[256];
  __shared__ float pooled[NH2];
  __shared__ int sidx[NSAMP];
  __shared__ float sc[3];
  const int cid = blockIdx.x;
  const int b = cid >> 11;
  const int s = cid & 2047;
  const int tid = threadIdx.x;
  if (tid < NSAMP) sidx[tid] = bidx[(size_t)cid * NSAMP + tid];
  if (tid < 3) sc[tid] = newxyz[(size_t)cid * 3 + tid];
  __syncthreads();
  {
    const int ss = tid >> 3, q = tid & 7;
    const int j = sidx[ss];
    if (useT) {
      const float4* fr = (const float4*)(fsrc + ((size_t)b * NN + j) * NC + q * 16);
#pragma unroll
      for (int u = 0; u < 4; ++u) {
        float4 v = fr[u];
        int c = 3 + q * 16 + u * 4;
        h[(c + 0) * HS + ss] = v.x;
        h[(c + 1) * HS + ss] = v.y;
        h[(c + 2) * HS + ss] = v.z;
        h[(c + 3) * HS + ss] = v.w;
      }
    } else {
      for (int u = 0; u < 16; ++u) {
        int c = q * 16 + u;
        h[(3 + c) * HS + ss] = fsrc[((size_t)b * NC + c) * NN + j];
      }
    }
    if (q == 0) {
      const float* pr = xyz + ((size_t)b * NN + j) * 3;
      h[0 * HS + ss] = pr[0] - sc[0];
      h[1 * HS + ss] = pr[1] - sc[1];
      h[2 * HS + ss] = pr[2] - sc[2];
    }
  }
  __syncthreads();
  {
    const int o = tid & 63, sg = tid >> 6;
    float acc[8];
    const float bb = b1[o];
#pragma unroll
    for (int i = 0; i < 8; ++i) acc[i] = bb;
    const float4* hb = (const float4*)&h[sg * 8];
    for (int k = 0; k < CIN; ++k) {
      float w = w1t[k * NH1 + o];
      float4 a = hb[k * (HS / 4) + 0];
      float4 c = hb[k * (HS / 4) + 1];
      acc[0] = fmaf(w, a.x, acc[0]); acc[1] = fmaf(w, a.y, acc[1]);
      acc[2] = fmaf(w, a.z, acc[2]); acc[3] = fmaf(w, a.w, acc[3]);
      acc[4] = fmaf(w, c.x, acc[4]); acc[5] = fmaf(w, c.y, acc[5]);
      acc[6] = fmaf(w, c.z, acc[6]); acc[7] = fmaf(w, c.w, acc[7]);
    }
#pragma unroll
    for (int i = 0; i < 8; ++i) h1[o * HS + sg * 8 + i] = fmaxf(acc[i], 0.0f);
  }
  __syncthreads();
  {
    const int o = tid & 127, sg = tid >> 7;
    float acc[16];
    const float bb = b2[o];
#pragma unroll
    for (int i = 0; i < 16; ++i) acc[i] = bb;
    const float4* hb = (const float4*)&h1[sg * 16];
    for (int k = 0; k < NH1; ++k) {
      float w = w2t[k * NH2 + o];
#pragma unroll
      for (int u = 0; u < 4; ++u) {
        float4 a = hb[k * (HS / 4) + u];
        acc[u * 4 + 0] = fmaf(w, a.x, acc[u * 4 + 0]);
        acc[u * 4 + 1] = fmaf(w, a.y, acc[u * 4 + 1]);
        acc[u * 4 + 2] = fmaf(w, a.z, acc[u * 4 + 2]);
        acc[u * 4 + 3] = fmaf(w, a.w, acc[u * 4 + 3]);
      }
    }
    float pm = acc[0];
#pragma unroll
    for (int i = 1; i < 16; ++i) pm = fmaxf(pm, acc[i]);
    pl[sg * 128 + o] = pm;
  }
  __syncthreads();
  if (tid < NH2) pooled[tid] = fmaxf(fmaxf(pl[tid], pl[128 + tid]), 0.0f);
  __syncthreads();
  if (tid < NOUTC) {
    float acc = bsa[tid];
    for (int k = 0; k < NH2; ++k) acc = fmaf(pooled[k], wsat[k * NOUTC + tid], acc);
    out1[((size_t)b * NOUTC + tid) * NPTS + s] = acc;
  }
}

extern "C" void kernel_launch(void* const* d_in, const int* in_sizes, int n_in,
                              void* d_out, int out_size, void* d_ws, size_t ws_size,
                              hipStream_t stream) {
  const float* xyz = (const float*)d_in[0];
  const float* feat = (const float*)d_in[1];
  const float* W1 = (const float*)d_in[2];
  const float* b1 = (const float*)d_in[3];
  const float* W2 = (const float*)d_in[4];
  const float* b2 = (const float*)d_in[5];
  const float* Wsa = (const float*)d_in[6];
  const float* bsa = (const float*)d_in[7];
  float* out = (float*)d_out;
  float* newxyz = out;                       // (B, NPTS, 3)
  float* out1 = out + (size_t)NB * NPTS * 3; // (B, OUT, NPTS)

  const size_t sort_f = (size_t)NB * NN * 4;  // xs, ys, zs, io
  const size_t small_f = (size_t)CIN * NH1 + NH1 * NH2 + NH2 * NOUTC +
                         (size_t)NB * NPTS * NSAMP;
  const size_t featT_f = (size_t)NB * NN * NC;

  float* ws = (float*)d_ws;
  bool useSort = ws_size >= (sort_f + small_f) * 4;
  bool useT = ws_size >= (sort_f + small_f + featT_f) * 4;

  float* xs = ws;
  float* ysr = xs + (size_t)NB * NN;
  float* zsr = ysr + (size_t)NB * NN;
  int* iosr = (int*)(zsr + (size_t)NB * NN);
  float* base2 = useSort ? (ws + sort_f) : ws;
  float* w1t = base2;
  float* w2t = w1t + CIN * NH1;
  float* wsat = w2t + NH1 * NH2;
  int* bidx = (int*)(wsat + NH2 * NOUTC);
  float* featT = (float*)(bidx + (size_t)NB * NPTS * NSAMP);

  tw_kernel<<<64, 256, 0, stream>>>(W1, W2, Wsa, w1t, w2t, wsat);
  if (useT)
    tfeat_kernel<<<dim3(NN / 32, NC / 32, NB), dim3(32, 8), 0, stream>>>(feat, featT);
  if (useSort) {
    sort_kernel<<<NB, 1024, 0, stream>>>(xyz, xs, ysr, zsr, iosr);
    fps_kernel<<<NB, 512, 0, stream>>>(xyz, xs, ysr, zsr, iosr, newxyz);
  } else {
    fps_nosort_kernel<<<NB, 1024, 0, stream>>>(xyz, newxyz);
  }
  ballq_kernel<<<NB * NPTS / 4, 256, 0, stream>>>(xyz, newxyz, bidx);
  mlp_kernel<<<NB * NPTS, 256, 0, stream>>>(xyz, useT ? featT : feat, newxyz, bidx,
                                            w1t, b1, w2t, b2, wsat, bsa, out1,
                                            (int)useT);
}